// Round 1
// baseline (1892.968 us; speedup 1.0000x reference)
//
#include <hip/hip_runtime.h>
#include <math.h>

namespace {

constexpr int B_ = 64;
constexpr int C_ = 192;
constexpr int H_ = 56;
constexpr int W_ = 56;
constexpr int HW_ = H_ * W_;          // 3136
constexpr int CHW_ = C_ * HW_;        // 602112
constexpr float PI_F = 3.14159265358979323846f;

// ---------------------------------------------------------------------------
// K0: DCT-II basis table  cos_tab[n][x] = cos(n*pi*(x+0.5)/56)*sqrt(2/56),
// row 0 additionally / sqrt(2).
// ---------------------------------------------------------------------------
__global__ void k_tables(float* __restrict__ cos_tab) {
  int i = blockIdx.x * 256 + threadIdx.x;
  if (i >= HW_) return;
  int n = i / W_;
  int x = i - n * W_;
  float wx = ((float)x + 0.5f) / 56.0f;
  float v = cosf(((float)n * wx) * PI_F) * 0.18898223650461362f; // sqrt(2/56)
  if (n == 0) v *= 0.7071067811865476f;
  cos_tab[i] = v;
}

// ---------------------------------------------------------------------------
// K_wexp: wexp[c][h*56+w] = exp(-relu(fe[h,w,:]@tok_w[:,c]+tok_b[c]) * (n_h^2+m_w^2))
// grid 196 blocks x 192 threads; each block does 16 spatial positions.
// ---------------------------------------------------------------------------
__global__ __launch_bounds__(192) void k_wexp(const float* __restrict__ fe,
                                              const float* __restrict__ tkw,
                                              const float* __restrict__ tkb,
                                              float* __restrict__ wexp) {
  __shared__ float sfe[16][C_];
  int hw0 = blockIdx.x * 16;
  int t = threadIdx.x;  // = output channel c
  for (int p = 0; p < 16; ++p) sfe[p][t] = fe[(size_t)(hw0 + p) * C_ + t];
  __syncthreads();
  float acc[16];
#pragma unroll
  for (int p = 0; p < 16; ++p) acc[p] = 0.f;
  for (int i = 0; i < C_; ++i) {
    float wv = tkw[i * C_ + t];
#pragma unroll
    for (int p = 0; p < 16; ++p) acc[p] = fmaf(sfe[p][i], wv, acc[p]);
  }
  float bias = tkb[t];
  const float step = PI_F / 56.0f;
#pragma unroll
  for (int p = 0; p < 16; ++p) {
    int hw = hw0 + p;
    int hh = hw / W_;
    int ww = hw - hh * W_;
    float nh = step * (float)hh;
    float nm = step * (float)ww;
    float a = nh * nh + nm * nm;
    float k = fmaxf(acc[p] + bias, 0.0f);
    wexp[(size_t)t * HW_ + hw] = expf(-k * a);
  }
}

// ---------------------------------------------------------------------------
// K1: depthwise 3x3 conv + bias, BCHW -> BCHW (y lives in d_out)
// ---------------------------------------------------------------------------
__global__ __launch_bounds__(256) void k_conv(const float* __restrict__ x,
                                              const float* __restrict__ dww,
                                              const float* __restrict__ dwb,
                                              float* __restrict__ y) {
  int idx = blockIdx.x * 256 + threadIdx.x;  // < 38,535,168
  int w = idx % W_;
  int t = idx / W_;
  int h = t % H_;
  t /= H_;
  int c = t % C_;
  int b = t / C_;
  const float* xb = x + (size_t)(b * C_ + c) * HW_;
  const float* wp = dww + c * 9;
  float acc = dwb[c];
#pragma unroll
  for (int di = -1; di <= 1; ++di) {
    int hh = h + di;
    if (hh < 0 || hh >= H_) continue;
#pragma unroll
    for (int dj = -1; dj <= 1; ++dj) {
      int ww = w + dj;
      if (ww < 0 || ww >= W_) continue;
      acc = fmaf(xb[hh * W_ + ww], wp[(di + 1) * 3 + (dj + 1)], acc);
    }
  }
  y[idx] = acc;
}

// ---------------------------------------------------------------------------
// K2: GEMM1  xz[pos, j] = y[pos, :] @ lin_w[:, j] + lin_b[j]
// A read from BCHW (A^T layout), outputs written as BCHW planes.
// tile 128(pos) x 128(j), thread 8x8, K-chunks of 16.
// ---------------------------------------------------------------------------
__global__ __launch_bounds__(256) void k_gemm1(const float* __restrict__ y,
                                               const float* __restrict__ lw,
                                               const float* __restrict__ lb,
                                               float* __restrict__ xp,
                                               float* __restrict__ zb) {
  __shared__ float sA[16][128];
  __shared__ float sB[16][128];
  int b = blockIdx.y;
  int pt = blockIdx.x % 25;
  int jt = blockIdx.x / 25;
  int pos0 = pt * 128;
  int j0 = jt * 128;
  const float* yb = y + (size_t)b * CHW_;
  int tid = threadIdx.x;
  int tx = tid % 16, ty = tid / 16;
  int p0 = tx * 8, q0 = ty * 8;
  float acc[8][8];
#pragma unroll
  for (int j = 0; j < 8; ++j)
#pragma unroll
    for (int i = 0; i < 8; ++i) acc[j][i] = 0.f;

  for (int cc = 0; cc < C_; cc += 16) {
#pragma unroll
    for (int r = 0; r < 8; ++r) {
      int e = tid + r * 256;
      int kr = e >> 7, pp = e & 127;
      int pos = pos0 + pp;
      sA[kr][pp] = (pos < HW_) ? yb[(size_t)(cc + kr) * HW_ + pos] : 0.0f;
      sB[kr][pp] = lw[(size_t)(cc + kr) * 384 + j0 + pp];
    }
    __syncthreads();
#pragma unroll
    for (int k = 0; k < 16; ++k) {
      const float4 a0 = *(const float4*)&sA[k][p0];
      const float4 a1 = *(const float4*)&sA[k][p0 + 4];
      const float4 b0 = *(const float4*)&sB[k][q0];
      const float4 b1 = *(const float4*)&sB[k][q0 + 4];
      const float av[8] = {a0.x, a0.y, a0.z, a0.w, a1.x, a1.y, a1.z, a1.w};
      const float bv[8] = {b0.x, b0.y, b0.z, b0.w, b1.x, b1.y, b1.z, b1.w};
#pragma unroll
      for (int j = 0; j < 8; ++j)
#pragma unroll
        for (int i = 0; i < 8; ++i) acc[j][i] = fmaf(av[i], bv[j], acc[j][i]);
    }
    __syncthreads();
  }
  if (pos0 + p0 < HW_) {  // 8-aligned, so all-or-nothing
#pragma unroll
    for (int j = 0; j < 8; ++j) {
      int jg = j0 + q0 + j;
      float bias = lb[jg];
      float* dst = (jg < C_) ? (xp + ((size_t)b * C_ + jg) * HW_)
                             : (zb + ((size_t)b * C_ + (jg - C_)) * HW_);
      float4 v0 = {acc[j][0] + bias, acc[j][1] + bias, acc[j][2] + bias, acc[j][3] + bias};
      float4 v1 = {acc[j][4] + bias, acc[j][5] + bias, acc[j][6] + bias, acc[j][7] + bias};
      *(float4*)&dst[pos0 + p0] = v0;
      *(float4*)&dst[pos0 + p0 + 4] = v1;
    }
  }
}

// ---------------------------------------------------------------------------
// K4: spectral sandwich per (b,c) plane:
//   S = Cn^T * ((Cn * P * Cm^T) .* Wc) * Cm
// one block (128 thr) per plane; 98 active threads compute 4x8 register tiles.
// ---------------------------------------------------------------------------
__global__ __launch_bounds__(128) void k_spec(const float* __restrict__ xp,
                                              const float* __restrict__ cos_tab,
                                              const float* __restrict__ wexp,
                                              float* __restrict__ sout) {
  constexpr int LDP = 60;
  __shared__ float scos[56 * LDP];
  __shared__ float bA[56 * LDP];
  __shared__ float bB[56 * LDP];
  const int bc = blockIdx.x;
  const int c = bc % C_;
  const float* __restrict__ P = xp + (size_t)bc * HW_;
  float* __restrict__ S = sout + (size_t)bc * HW_;
  const float* __restrict__ wx = wexp + (size_t)c * HW_;
  const int tid = threadIdx.x;
  for (int e = tid; e < HW_; e += 128) {
    int r = e / 56, q = e - r * 56;
    scos[r * LDP + q] = cos_tab[e];
    bA[r * LDP + q] = P[e];
  }
  __syncthreads();
  const bool act = tid < 98;
  const int i0 = (tid / 7) * 4;
  const int j0 = (tid % 7) * 8;
  float acc[4][8];

  // mm1: bB[n][w] = sum_h scos[n][h] * bA[h][w]
  if (act) {
#pragma unroll
    for (int i = 0; i < 4; ++i)
#pragma unroll
      for (int j = 0; j < 8; ++j) acc[i][j] = 0.f;
    for (int h = 0; h < 56; ++h) {
      float aa[4];
#pragma unroll
      for (int i = 0; i < 4; ++i) aa[i] = scos[(i0 + i) * LDP + h];
      float4 p0 = *(const float4*)&bA[h * LDP + j0];
      float4 p1 = *(const float4*)&bA[h * LDP + j0 + 4];
      const float pv[8] = {p0.x, p0.y, p0.z, p0.w, p1.x, p1.y, p1.z, p1.w};
#pragma unroll
      for (int i = 0; i < 4; ++i)
#pragma unroll
        for (int j = 0; j < 8; ++j) acc[i][j] = fmaf(aa[i], pv[j], acc[i][j]);
    }
#pragma unroll
    for (int i = 0; i < 4; ++i) {
      float4 v0 = {acc[i][0], acc[i][1], acc[i][2], acc[i][3]};
      float4 v1 = {acc[i][4], acc[i][5], acc[i][6], acc[i][7]};
      *(float4*)&bB[(i0 + i) * LDP + j0] = v0;
      *(float4*)&bB[(i0 + i) * LDP + j0 + 4] = v1;
    }
  }
  __syncthreads();

  // mm2: bA[n][m] = (sum_w bB[n][w] * scos[m][w]) * wexp[n][m]   (dot-style)
  if (act) {
#pragma unroll
    for (int i = 0; i < 4; ++i)
#pragma unroll
      for (int j = 0; j < 8; ++j) acc[i][j] = 0.f;
    for (int k = 0; k < 56; k += 4) {
      float4 t0 = *(const float4*)&bB[(i0 + 0) * LDP + k];
      float4 t1 = *(const float4*)&bB[(i0 + 1) * LDP + k];
      float4 t2 = *(const float4*)&bB[(i0 + 2) * LDP + k];
      float4 t3 = *(const float4*)&bB[(i0 + 3) * LDP + k];
#pragma unroll
      for (int j = 0; j < 8; ++j) {
        float4 cv = *(const float4*)&scos[(j0 + j) * LDP + k];
        acc[0][j] = fmaf(t0.x, cv.x, fmaf(t0.y, cv.y, fmaf(t0.z, cv.z, fmaf(t0.w, cv.w, acc[0][j]))));
        acc[1][j] = fmaf(t1.x, cv.x, fmaf(t1.y, cv.y, fmaf(t1.z, cv.z, fmaf(t1.w, cv.w, acc[1][j]))));
        acc[2][j] = fmaf(t2.x, cv.x, fmaf(t2.y, cv.y, fmaf(t2.z, cv.z, fmaf(t2.w, cv.w, acc[2][j]))));
        acc[3][j] = fmaf(t3.x, cv.x, fmaf(t3.y, cv.y, fmaf(t3.z, cv.z, fmaf(t3.w, cv.w, acc[3][j]))));
      }
    }
#pragma unroll
    for (int i = 0; i < 4; ++i) {
      float4 w0 = *(const float4*)&wx[(i0 + i) * 56 + j0];
      float4 w1 = *(const float4*)&wx[(i0 + i) * 56 + j0 + 4];
      float4 v0 = {acc[i][0] * w0.x, acc[i][1] * w0.y, acc[i][2] * w0.z, acc[i][3] * w0.w};
      float4 v1 = {acc[i][4] * w1.x, acc[i][5] * w1.y, acc[i][6] * w1.z, acc[i][7] * w1.w};
      *(float4*)&bA[(i0 + i) * LDP + j0] = v0;
      *(float4*)&bA[(i0 + i) * LDP + j0 + 4] = v1;
    }
  }
  __syncthreads();

  // mm3: bB[h][m] = sum_n scos[n][h] * bA[n][m]   (outer-style, both vectorized)
  if (act) {
#pragma unroll
    for (int i = 0; i < 4; ++i)
#pragma unroll
      for (int j = 0; j < 8; ++j) acc[i][j] = 0.f;
    for (int k = 0; k < 56; ++k) {
      float4 av = *(const float4*)&scos[k * LDP + i0];
      float4 g0 = *(const float4*)&bA[k * LDP + j0];
      float4 g1 = *(const float4*)&bA[k * LDP + j0 + 4];
      const float aa[4] = {av.x, av.y, av.z, av.w};
      const float gv[8] = {g0.x, g0.y, g0.z, g0.w, g1.x, g1.y, g1.z, g1.w};
#pragma unroll
      for (int i = 0; i < 4; ++i)
#pragma unroll
        for (int j = 0; j < 8; ++j) acc[i][j] = fmaf(aa[i], gv[j], acc[i][j]);
    }
#pragma unroll
    for (int i = 0; i < 4; ++i) {
      float4 v0 = {acc[i][0], acc[i][1], acc[i][2], acc[i][3]};
      float4 v1 = {acc[i][4], acc[i][5], acc[i][6], acc[i][7]};
      *(float4*)&bB[(i0 + i) * LDP + j0] = v0;
      *(float4*)&bB[(i0 + i) * LDP + j0 + 4] = v1;
    }
  }
  __syncthreads();

  // mm4: S[h][w] = sum_m bB[h][m] * scos[m][w]
  if (act) {
#pragma unroll
    for (int i = 0; i < 4; ++i)
#pragma unroll
      for (int j = 0; j < 8; ++j) acc[i][j] = 0.f;
    for (int k = 0; k < 56; ++k) {
      float aa[4];
#pragma unroll
      for (int i = 0; i < 4; ++i) aa[i] = bB[(i0 + i) * LDP + k];
      float4 c0 = *(const float4*)&scos[k * LDP + j0];
      float4 c1 = *(const float4*)&scos[k * LDP + j0 + 4];
      const float cv[8] = {c0.x, c0.y, c0.z, c0.w, c1.x, c1.y, c1.z, c1.w};
#pragma unroll
      for (int i = 0; i < 4; ++i)
#pragma unroll
        for (int j = 0; j < 8; ++j) acc[i][j] = fmaf(aa[i], cv[j], acc[i][j]);
    }
#pragma unroll
    for (int i = 0; i < 4; ++i) {
      float4 v0 = {acc[i][0], acc[i][1], acc[i][2], acc[i][3]};
      float4 v1 = {acc[i][4], acc[i][5], acc[i][6], acc[i][7]};
      *(float4*)&S[(i0 + i) * 56 + j0] = v0;
      *(float4*)&S[(i0 + i) * 56 + j0 + 4] = v1;
    }
  }
}

// ---------------------------------------------------------------------------
// K5: LayerNorm(C) -> *silu(z) -> GEMM2 (192x192) + bias -> d_out (BCHW)
// NOTE: s aliases out (d_out). Each block fully stages its read-region in LDS
// before writing the identical region -> in-place safe. No __restrict__ here.
// ---------------------------------------------------------------------------
__global__ __launch_bounds__(256) void k_ln_gemm2(const float* s, const float* z,
                                                  const float* __restrict__ gamma,
                                                  const float* __restrict__ beta,
                                                  const float* __restrict__ ow,
                                                  const float* __restrict__ ob,
                                                  float* out) {
  __shared__ float sA[C_][64];
  __shared__ float sB[32][C_];
  __shared__ float red[8][64];
  __shared__ float smu[64], srs[64];
  int b = blockIdx.y;
  int pos0 = blockIdx.x * 64;
  const float* sbp = s + (size_t)b * CHW_ + pos0;
  const float* zbp = z + (size_t)b * CHW_ + pos0;
  int tid = threadIdx.x;
  int p = tid % 64, cr = tid / 64;
  float sum = 0.f, sq = 0.f;
  for (int c = cr; c < C_; c += 4) {
    float v = sbp[(size_t)c * HW_ + p];
    sA[c][p] = v;
    sum += v;
    sq = fmaf(v, v, sq);
  }
  red[cr][p] = sum;
  red[4 + cr][p] = sq;
  __syncthreads();
  if (tid < 64) {
    float s1 = red[0][tid] + red[1][tid] + red[2][tid] + red[3][tid];
    float s2 = red[4][tid] + red[5][tid] + red[6][tid] + red[7][tid];
    float mu = s1 * (1.0f / 192.0f);
    float var = s2 * (1.0f / 192.0f) - mu * mu;
    smu[tid] = mu;
    srs[tid] = rsqrtf(var + 1e-5f);
  }
  __syncthreads();
  float mu = smu[p], rs = srs[p];
  for (int c = cr; c < C_; c += 4) {
    float v = sA[c][p];
    v = (v - mu) * rs * gamma[c] + beta[c];
    float zz = zbp[(size_t)c * HW_ + p];
    v *= zz / (1.0f + expf(-zz));
    sA[c][p] = v;
  }
  __syncthreads();

  int tp = tid % 16, tj = tid / 16;
  int pp0 = tp * 4, jj0 = tj * 12;
  float acc[12][4];
#pragma unroll
  for (int j = 0; j < 12; ++j)
#pragma unroll
    for (int i = 0; i < 4; ++i) acc[j][i] = 0.f;

  for (int cc = 0; cc < C_; cc += 32) {
#pragma unroll
    for (int r = 0; r < 24; ++r) {
      int e = tid + r * 256;
      int kr = e / C_, col = e - kr * C_;
      sB[kr][col] = ow[(size_t)(cc + kr) * C_ + col];
    }
    __syncthreads();
#pragma unroll
    for (int k = 0; k < 32; ++k) {
      float4 a = *(const float4*)&sA[cc + k][pp0];
      float4 b0 = *(const float4*)&sB[k][jj0];
      float4 b1 = *(const float4*)&sB[k][jj0 + 4];
      float4 b2 = *(const float4*)&sB[k][jj0 + 8];
      const float av[4] = {a.x, a.y, a.z, a.w};
      const float bv[12] = {b0.x, b0.y, b0.z, b0.w, b1.x, b1.y,
                            b1.z, b1.w, b2.x, b2.y, b2.z, b2.w};
#pragma unroll
      for (int j = 0; j < 12; ++j)
#pragma unroll
        for (int i = 0; i < 4; ++i) acc[j][i] = fmaf(av[i], bv[j], acc[j][i]);
    }
    __syncthreads();
  }
  float* op = out + (size_t)b * CHW_ + pos0;
#pragma unroll
  for (int j = 0; j < 12; ++j) {
    int jg = jj0 + j;
    float bias = ob[jg];
    float4 v = {acc[j][0] + bias, acc[j][1] + bias, acc[j][2] + bias, acc[j][3] + bias};
    *(float4*)&op[(size_t)jg * HW_ + pp0] = v;
  }
}

}  // namespace

extern "C" void kernel_launch(void* const* d_in, const int* in_sizes, int n_in,
                              void* d_out, int out_size, void* d_ws, size_t ws_size,
                              hipStream_t stream) {
  const float* x = (const float*)d_in[0];
  const float* dww = (const float*)d_in[1];
  const float* dwb = (const float*)d_in[2];
  const float* lw = (const float*)d_in[3];
  const float* lb = (const float*)d_in[4];
  const float* tkw = (const float*)d_in[5];
  const float* tkb = (const float*)d_in[6];
  const float* fe = (const float*)d_in[7];
  const float* gamma = (const float*)d_in[8];
  const float* beta = (const float*)d_in[9];
  const float* ow = (const float*)d_in[10];
  const float* obias = (const float*)d_in[11];
  float* out = (float*)d_out;

  float* ws = (float*)d_ws;
  float* cos_tab = ws;                      // 3136
  float* wexp = cos_tab + HW_;              // 602112
  float* xp = wexp + CHW_;                  // 38535168
  float* zb = xp + (size_t)B_ * CHW_;       // 38535168
  float* y = out;                           // d_out doubles as conv-out, then spectral-out

  hipLaunchKernelGGL(k_tables, dim3(13), dim3(256), 0, stream, cos_tab);
  hipLaunchKernelGGL(k_wexp, dim3(HW_ / 16), dim3(192), 0, stream, fe, tkw, tkb, wexp);
  hipLaunchKernelGGL(k_conv, dim3((B_ * CHW_) / 256), dim3(256), 0, stream, x, dww, dwb, y);
  hipLaunchKernelGGL(k_gemm1, dim3(75, 64), dim3(256), 0, stream, y, lw, lb, xp, zb);
  hipLaunchKernelGGL(k_spec, dim3(B_ * C_), dim3(128), 0, stream, xp, cos_tab, wexp, y);
  hipLaunchKernelGGL(k_ln_gemm2, dim3(HW_ / 64, 64), dim3(256), 0, stream, y, zb, gamma, beta,
                     ow, obias, out);
}

// Round 2
// 1069.510 us; speedup vs baseline: 1.7699x; 1.7699x over previous
//
#include <hip/hip_runtime.h>
#include <math.h>

namespace {

constexpr int B_ = 64;
constexpr int C_ = 192;
constexpr int H_ = 56;
constexpr int W_ = 56;
constexpr int HW_ = H_ * W_;          // 3136
constexpr int CHW_ = C_ * HW_;        // 602112
constexpr float PI_F = 3.14159265358979323846f;

typedef __attribute__((ext_vector_type(8))) short short8;
typedef __attribute__((ext_vector_type(4))) float f32x4;

__device__ inline unsigned short f2bf(float f) {
  union { float f; unsigned u; } v{f};
  unsigned r = v.u + 0x7FFFu + ((v.u >> 16) & 1u);
  return (unsigned short)(r >> 16);
}

// act/LDS xor swizzle for [row][c] bf16 tiles with row stride 200 elems
__device__ inline int swz(int row) { return ((row >> 1) & 7) << 3; }

// ---------------------------------------------------------------------------
// K0: DCT-II basis table
// ---------------------------------------------------------------------------
__global__ void k_tables(float* __restrict__ cos_tab) {
  int i = blockIdx.x * 256 + threadIdx.x;
  if (i >= HW_) return;
  int n = i / W_;
  int x = i - n * W_;
  float wx = ((float)x + 0.5f) / 56.0f;
  float v = cosf(((float)n * wx) * PI_F) * 0.18898223650461362f;
  if (n == 0) v *= 0.7071067811865476f;
  cos_tab[i] = v;
}

// ---------------------------------------------------------------------------
// K_wexp: wexp[c][hw] = exp(-relu(fe@tok_w+tok_b) * (n^2+m^2))
// ---------------------------------------------------------------------------
__global__ __launch_bounds__(192) void k_wexp(const float* __restrict__ fe,
                                              const float* __restrict__ tkw,
                                              const float* __restrict__ tkb,
                                              float* __restrict__ wexp) {
  __shared__ float sfe[16][C_];
  int hw0 = blockIdx.x * 16;
  int t = threadIdx.x;
  for (int p = 0; p < 16; ++p) sfe[p][t] = fe[(size_t)(hw0 + p) * C_ + t];
  __syncthreads();
  float acc[16];
#pragma unroll
  for (int p = 0; p < 16; ++p) acc[p] = 0.f;
  for (int i = 0; i < C_; ++i) {
    float wv = tkw[i * C_ + t];
#pragma unroll
    for (int p = 0; p < 16; ++p) acc[p] = fmaf(sfe[p][i], wv, acc[p]);
  }
  float bias = tkb[t];
  const float step = PI_F / 56.0f;
#pragma unroll
  for (int p = 0; p < 16; ++p) {
    int hw = hw0 + p;
    int hh = hw / W_;
    int ww = hw - hh * W_;
    float nh = step * (float)hh;
    float nm = step * (float)ww;
    float a = nh * nh + nm * nm;
    float k = fmaxf(acc[p] + bias, 0.0f);
    wexp[(size_t)t * HW_ + hw] = expf(-k * a);
  }
}

// ---------------------------------------------------------------------------
// K_prep_w: lwT[j][c] = bf16(lin_w[c][j]) (384x192), owT[j][c] = bf16(out_w[c][j])
// ---------------------------------------------------------------------------
__global__ __launch_bounds__(256) void k_prep_w(const float* __restrict__ lw,
                                                const float* __restrict__ ow,
                                                unsigned short* __restrict__ lwT,
                                                unsigned short* __restrict__ owT) {
  int i = blockIdx.x * 256 + threadIdx.x;
  if (i < 384 * 192) {
    int j = i / 192, c = i - j * 192;
    lwT[i] = f2bf(lw[c * 384 + j]);
  } else if (i < 384 * 192 + 192 * 192) {
    int k = i - 384 * 192;
    int j = k / 192, c = k - j * 192;
    owT[k] = f2bf(ow[c * 192 + j]);
  }
}

// ---------------------------------------------------------------------------
// K1: depthwise 3x3 conv + bias (fp32, BCHW -> BCHW in d_out)
// ---------------------------------------------------------------------------
__global__ __launch_bounds__(256) void k_conv(const float* __restrict__ x,
                                              const float* __restrict__ dww,
                                              const float* __restrict__ dwb,
                                              float* __restrict__ y) {
  int idx = blockIdx.x * 256 + threadIdx.x;
  int w = idx % W_;
  int t = idx / W_;
  int h = t % H_;
  t /= H_;
  int c = t % C_;
  int b = t / C_;
  const float* xb = x + (size_t)(b * C_ + c) * HW_;
  const float* wp = dww + c * 9;
  float acc = dwb[c];
#pragma unroll
  for (int di = -1; di <= 1; ++di) {
    int hh = h + di;
    if (hh < 0 || hh >= H_) continue;
#pragma unroll
    for (int dj = -1; dj <= 1; ++dj) {
      int ww = w + dj;
      if (ww < 0 || ww >= W_) continue;
      acc = fmaf(xb[hh * W_ + ww], wp[(di + 1) * 3 + (dj + 1)], acc);
    }
  }
  y[idx] = acc;
}

// ---------------------------------------------------------------------------
// K_t: y fp32 [b][c][pos] -> yT bf16 [b][pos][c]  (64-pos tile per block)
// ---------------------------------------------------------------------------
__global__ __launch_bounds__(256) void k_t(const float* __restrict__ y,
                                           unsigned short* __restrict__ yT) {
  __shared__ unsigned short t[64 * 200];
  int b = blockIdx.y, pt = blockIdx.x;
  int tid = threadIdx.x;
  int p = tid & 63, cr = tid >> 6;
  const float* yb = y + (size_t)b * CHW_ + pt * 64;
#pragma unroll
  for (int i = 0; i < 48; ++i) {
    int c = cr + 4 * i;
    t[p * 200 + (c ^ swz(p))] = f2bf(yb[(size_t)c * HW_ + p]);
  }
  __syncthreads();
  unsigned short* o = yT + ((size_t)b * HW_ + pt * 64) * C_;
#pragma unroll
  for (int q = 0; q < 6; ++q) {
    int idx = q * 256 + tid;          // < 1536
    int pos = idx / 24, cb = idx % 24;
    short8 v = *(const short8*)&t[pos * 200 + ((cb * 8) ^ swz(pos))];
    *(short8*)&o[(size_t)idx * 8] = v;
  }
}

// ---------------------------------------------------------------------------
// K2: GEMM1 via MFMA bf16.  D[j 384][pos 3136] = lwT[j][c] * yT[pos][c]^T
// 128x128 tile, 4 waves (2x2), K-chunks of 32. Outputs fp32 planes xp / zb.
// ---------------------------------------------------------------------------
__global__ __launch_bounds__(256) void k_gemm1(const unsigned short* __restrict__ yT,
                                               const unsigned short* __restrict__ lwT,
                                               const float* __restrict__ lb,
                                               float* __restrict__ xp,
                                               float* __restrict__ zb) {
  constexpr int LD = 40;              // pad: rows 16B-aligned, 2-way banks
  __shared__ unsigned short sA[128 * LD];
  __shared__ unsigned short sY[128 * LD];
  int b = blockIdx.y;
  int bx = blockIdx.x;                // 75 -> bijective XCD swizzle (q=9,r=3)
  int xcd = bx & 7, o8 = bx >> 3;
  int lg = (xcd < 3 ? xcd * 10 : 30 + (xcd - 3) * 9) + o8;
  int pt = lg / 3, jt = lg % 3;
  int pos0 = pt * 128, j0 = jt * 128;
  int tid = threadIdx.x, lane = tid & 63, wv = tid >> 6;
  int wm = wv & 1, wn = wv >> 1;

  int row0 = tid >> 2, row1 = 64 + (tid >> 2), cb = (tid & 3) * 8;
  const unsigned short* a0 = lwT + (size_t)(j0 + row0) * C_ + cb;
  const unsigned short* a1 = lwT + (size_t)(j0 + row1) * C_ + cb;
  int pr0 = pos0 + row0; if (pr0 > HW_ - 1) pr0 = HW_ - 1;
  int pr1 = pos0 + row1; if (pr1 > HW_ - 1) pr1 = HW_ - 1;
  const unsigned short* b0 = yT + ((size_t)b * HW_ + pr0) * C_ + cb;
  const unsigned short* b1 = yT + ((size_t)b * HW_ + pr1) * C_ + cb;
  int d0 = row0 * LD + cb, d1 = row1 * LD + cb;

  f32x4 acc[4][4] = {};
  for (int kk = 0; kk < C_; kk += 32) {
    short8 va0 = *(const short8*)(a0 + kk);
    short8 va1 = *(const short8*)(a1 + kk);
    short8 vb0 = *(const short8*)(b0 + kk);
    short8 vb1 = *(const short8*)(b1 + kk);
    if (kk) __syncthreads();
    *(short8*)&sA[d0] = va0;
    *(short8*)&sA[d1] = va1;
    *(short8*)&sY[d0] = vb0;
    *(short8*)&sY[d1] = vb1;
    __syncthreads();
    int ra = (wm * 64 + (lane & 15)) * LD + (lane >> 4) * 8;
    int rb = (wn * 64 + (lane & 15)) * LD + (lane >> 4) * 8;
    short8 af[4], bf[4];
#pragma unroll
    for (int m = 0; m < 4; ++m) af[m] = *(const short8*)&sA[ra + m * 16 * LD];
#pragma unroll
    for (int n = 0; n < 4; ++n) bf[n] = *(const short8*)&sY[rb + n * 16 * LD];
#pragma unroll
    for (int m = 0; m < 4; ++m)
#pragma unroll
      for (int n = 0; n < 4; ++n)
        acc[m][n] = __builtin_amdgcn_mfma_f32_16x16x32_bf16(af[m], bf[n], acc[m][n], 0, 0, 0);
  }

#pragma unroll
  for (int m = 0; m < 4; ++m) {
    int jb = j0 + wm * 64 + m * 16 + (lane >> 4) * 4;
#pragma unroll
    for (int r = 0; r < 4; ++r) {
      int jg = jb + r;
      float bias = lb[jg];
      float* base = (jg < C_) ? (xp + ((size_t)b * C_ + jg) * HW_)
                              : (zb + ((size_t)b * C_ + (jg - C_)) * HW_);
#pragma unroll
      for (int n = 0; n < 4; ++n) {
        int pos = pos0 + wn * 64 + n * 16 + (lane & 15);
        if (pos < HW_) base[pos] = acc[m][n][r] + bias;
      }
    }
  }
}

// ---------------------------------------------------------------------------
// K4: spectral sandwich per (b,c) plane (fp32; in-place on d_out)
// ---------------------------------------------------------------------------
__global__ __launch_bounds__(128) void k_spec(const float* xp,
                                              const float* __restrict__ cos_tab,
                                              const float* __restrict__ wexp,
                                              float* sout) {
  constexpr int LDP = 60;
  __shared__ float scos[56 * LDP];
  __shared__ float bA[56 * LDP];
  __shared__ float bB[56 * LDP];
  const int bc = blockIdx.x;
  const int c = bc % C_;
  const float* P = xp + (size_t)bc * HW_;
  float* S = sout + (size_t)bc * HW_;
  const float* __restrict__ wx = wexp + (size_t)c * HW_;
  const int tid = threadIdx.x;
  for (int e = tid; e < HW_; e += 128) {
    int r = e / 56, q = e - r * 56;
    scos[r * LDP + q] = cos_tab[e];
    bA[r * LDP + q] = P[e];
  }
  __syncthreads();
  const bool act = tid < 98;
  const int i0 = (tid / 7) * 4;
  const int j0 = (tid % 7) * 8;
  float acc[4][8];

  if (act) {
#pragma unroll
    for (int i = 0; i < 4; ++i)
#pragma unroll
      for (int j = 0; j < 8; ++j) acc[i][j] = 0.f;
    for (int h = 0; h < 56; ++h) {
      float aa[4];
#pragma unroll
      for (int i = 0; i < 4; ++i) aa[i] = scos[(i0 + i) * LDP + h];
      float4 p0 = *(const float4*)&bA[h * LDP + j0];
      float4 p1 = *(const float4*)&bA[h * LDP + j0 + 4];
      const float pv[8] = {p0.x, p0.y, p0.z, p0.w, p1.x, p1.y, p1.z, p1.w};
#pragma unroll
      for (int i = 0; i < 4; ++i)
#pragma unroll
        for (int j = 0; j < 8; ++j) acc[i][j] = fmaf(aa[i], pv[j], acc[i][j]);
    }
#pragma unroll
    for (int i = 0; i < 4; ++i) {
      float4 v0 = {acc[i][0], acc[i][1], acc[i][2], acc[i][3]};
      float4 v1 = {acc[i][4], acc[i][5], acc[i][6], acc[i][7]};
      *(float4*)&bB[(i0 + i) * LDP + j0] = v0;
      *(float4*)&bB[(i0 + i) * LDP + j0 + 4] = v1;
    }
  }
  __syncthreads();

  if (act) {
#pragma unroll
    for (int i = 0; i < 4; ++i)
#pragma unroll
      for (int j = 0; j < 8; ++j) acc[i][j] = 0.f;
    for (int k = 0; k < 56; k += 4) {
      float4 t0 = *(const float4*)&bB[(i0 + 0) * LDP + k];
      float4 t1 = *(const float4*)&bB[(i0 + 1) * LDP + k];
      float4 t2 = *(const float4*)&bB[(i0 + 2) * LDP + k];
      float4 t3 = *(const float4*)&bB[(i0 + 3) * LDP + k];
#pragma unroll
      for (int j = 0; j < 8; ++j) {
        float4 cv = *(const float4*)&scos[(j0 + j) * LDP + k];
        acc[0][j] = fmaf(t0.x, cv.x, fmaf(t0.y, cv.y, fmaf(t0.z, cv.z, fmaf(t0.w, cv.w, acc[0][j]))));
        acc[1][j] = fmaf(t1.x, cv.x, fmaf(t1.y, cv.y, fmaf(t1.z, cv.z, fmaf(t1.w, cv.w, acc[1][j]))));
        acc[2][j] = fmaf(t2.x, cv.x, fmaf(t2.y, cv.y, fmaf(t2.z, cv.z, fmaf(t2.w, cv.w, acc[2][j]))));
        acc[3][j] = fmaf(t3.x, cv.x, fmaf(t3.y, cv.y, fmaf(t3.z, cv.z, fmaf(t3.w, cv.w, acc[3][j]))));
      }
    }
#pragma unroll
    for (int i = 0; i < 4; ++i) {
      float4 w0 = *(const float4*)&wx[(i0 + i) * 56 + j0];
      float4 w1 = *(const float4*)&wx[(i0 + i) * 56 + j0 + 4];
      float4 v0 = {acc[i][0] * w0.x, acc[i][1] * w0.y, acc[i][2] * w0.z, acc[i][3] * w0.w};
      float4 v1 = {acc[i][4] * w1.x, acc[i][5] * w1.y, acc[i][6] * w1.z, acc[i][7] * w1.w};
      *(float4*)&bA[(i0 + i) * LDP + j0] = v0;
      *(float4*)&bA[(i0 + i) * LDP + j0 + 4] = v1;
    }
  }
  __syncthreads();

  if (act) {
#pragma unroll
    for (int i = 0; i < 4; ++i)
#pragma unroll
      for (int j = 0; j < 8; ++j) acc[i][j] = 0.f;
    for (int k = 0; k < 56; ++k) {
      float4 av = *(const float4*)&scos[k * LDP + i0];
      float4 g0 = *(const float4*)&bA[k * LDP + j0];
      float4 g1 = *(const float4*)&bA[k * LDP + j0 + 4];
      const float aa[4] = {av.x, av.y, av.z, av.w};
      const float gv[8] = {g0.x, g0.y, g0.z, g0.w, g1.x, g1.y, g1.z, g1.w};
#pragma unroll
      for (int i = 0; i < 4; ++i)
#pragma unroll
        for (int j = 0; j < 8; ++j) acc[i][j] = fmaf(aa[i], gv[j], acc[i][j]);
    }
#pragma unroll
    for (int i = 0; i < 4; ++i) {
      float4 v0 = {acc[i][0], acc[i][1], acc[i][2], acc[i][3]};
      float4 v1 = {acc[i][4], acc[i][5], acc[i][6], acc[i][7]};
      *(float4*)&bB[(i0 + i) * LDP + j0] = v0;
      *(float4*)&bB[(i0 + i) * LDP + j0 + 4] = v1;
    }
  }
  __syncthreads();

  if (act) {
#pragma unroll
    for (int i = 0; i < 4; ++i)
#pragma unroll
      for (int j = 0; j < 8; ++j) acc[i][j] = 0.f;
    for (int k = 0; k < 56; ++k) {
      float aa[4];
#pragma unroll
      for (int i = 0; i < 4; ++i) aa[i] = bB[(i0 + i) * LDP + k];
      float4 c0 = *(const float4*)&scos[k * LDP + j0];
      float4 c1 = *(const float4*)&scos[k * LDP + j0 + 4];
      const float cv[8] = {c0.x, c0.y, c0.z, c0.w, c1.x, c1.y, c1.z, c1.w};
#pragma unroll
      for (int i = 0; i < 4; ++i)
#pragma unroll
        for (int j = 0; j < 8; ++j) acc[i][j] = fmaf(aa[i], cv[j], acc[i][j]);
    }
#pragma unroll
    for (int i = 0; i < 4; ++i) {
      float4 v0 = {acc[i][0], acc[i][1], acc[i][2], acc[i][3]};
      float4 v1 = {acc[i][4], acc[i][5], acc[i][6], acc[i][7]};
      *(float4*)&S[(i0 + i) * 56 + j0] = v0;
      *(float4*)&S[(i0 + i) * 56 + j0 + 4] = v1;
    }
  }
}

// ---------------------------------------------------------------------------
// K5: LayerNorm -> silu-gate -> GEMM2 via MFMA bf16.
// Block: 64 pos x all 192 j. s aliases out (reads finish before writes).
// ---------------------------------------------------------------------------
__global__ __launch_bounds__(256) void k_ln2(const float* s, const float* z,
                                             const float* __restrict__ gamma,
                                             const float* __restrict__ beta,
                                             const unsigned short* __restrict__ owT,
                                             const float* __restrict__ ob,
                                             float* out) {
  constexpr int LDB2 = 40;
  __shared__ unsigned short act[64 * 200];
  __shared__ unsigned short sB[192 * LDB2];
  __shared__ float red[8][64];
  __shared__ float smu[64], srs[64];
  int b = blockIdx.y, pt = blockIdx.x;
  int tid = threadIdx.x, lane = tid & 63, wv = tid >> 6;
  int p = tid & 63, cr = tid >> 6;
  const float* sp = s + (size_t)b * CHW_ + pt * 64 + p;
  const float* zp = z + (size_t)b * CHW_ + pt * 64 + p;
  float sv[48];
  float sum = 0.f, sq = 0.f;
#pragma unroll
  for (int i = 0; i < 48; ++i) {
    float v = sp[(size_t)(cr + 4 * i) * HW_];
    sv[i] = v;
    sum += v;
    sq = fmaf(v, v, sq);
  }
  red[cr][p] = sum;
  red[4 + cr][p] = sq;
  __syncthreads();
  if (tid < 64) {
    float s1 = red[0][tid] + red[1][tid] + red[2][tid] + red[3][tid];
    float s2 = red[4][tid] + red[5][tid] + red[6][tid] + red[7][tid];
    float mu = s1 * (1.0f / 192.0f);
    float var = s2 * (1.0f / 192.0f) - mu * mu;
    smu[tid] = mu;
    srs[tid] = rsqrtf(var + 1e-5f);
  }
  __syncthreads();
  float mu = smu[p], rs = srs[p];
#pragma unroll
  for (int i = 0; i < 48; ++i) {
    int c = cr + 4 * i;
    float v = (sv[i] - mu) * rs * gamma[c] + beta[c];
    float zz = zp[(size_t)c * HW_];
    v *= zz / (1.0f + expf(-zz));
    act[p * 200 + (c ^ swz(p))] = f2bf(v);
  }

  f32x4 acc[3][4] = {};
  for (int kk = 0; kk < C_; kk += 32) {
    short8 w0, w1, w2;
    {
      int i0 = tid, i1 = tid + 256, i2 = tid + 512;
      w0 = *(const short8*)&owT[(size_t)(i0 >> 2) * C_ + kk + (i0 & 3) * 8];
      w1 = *(const short8*)&owT[(size_t)(i1 >> 2) * C_ + kk + (i1 & 3) * 8];
      w2 = *(const short8*)&owT[(size_t)(i2 >> 2) * C_ + kk + (i2 & 3) * 8];
    }
    __syncthreads();   // act ready (1st iter) / prev frag reads done
    {
      int i0 = tid, i1 = tid + 256, i2 = tid + 512;
      *(short8*)&sB[(i0 >> 2) * LDB2 + (i0 & 3) * 8] = w0;
      *(short8*)&sB[(i1 >> 2) * LDB2 + (i1 & 3) * 8] = w1;
      *(short8*)&sB[(i2 >> 2) * LDB2 + (i2 & 3) * 8] = w2;
    }
    __syncthreads();
    short8 af[3], bf[4];
    int ra = (wv * 48 + (lane & 15)) * LDB2 + (lane >> 4) * 8;
#pragma unroll
    for (int m = 0; m < 3; ++m) af[m] = *(const short8*)&sB[ra + m * 16 * LDB2];
#pragma unroll
    for (int n = 0; n < 4; ++n) {
      int row = (lane & 15) + 16 * n;
      int co = (kk + (lane >> 4) * 8) ^ swz(row);
      bf[n] = *(const short8*)&act[row * 200 + co];
    }
#pragma unroll
    for (int m = 0; m < 3; ++m)
#pragma unroll
      for (int n = 0; n < 4; ++n)
        acc[m][n] = __builtin_amdgcn_mfma_f32_16x16x32_bf16(af[m], bf[n], acc[m][n], 0, 0, 0);
  }

  float* op = out + (size_t)b * CHW_ + pt * 64;
#pragma unroll
  for (int m = 0; m < 3; ++m) {
    int jb = wv * 48 + m * 16 + (lane >> 4) * 4;
#pragma unroll
    for (int r = 0; r < 4; ++r) {
      int j = jb + r;
      float bias = ob[j];
#pragma unroll
      for (int n = 0; n < 4; ++n) {
        int pos = n * 16 + (lane & 15);
        op[(size_t)j * HW_ + pos] = acc[m][n][r] + bias;
      }
    }
  }
}

}  // namespace

extern "C" void kernel_launch(void* const* d_in, const int* in_sizes, int n_in,
                              void* d_out, int out_size, void* d_ws, size_t ws_size,
                              hipStream_t stream) {
  const float* x = (const float*)d_in[0];
  const float* dww = (const float*)d_in[1];
  const float* dwb = (const float*)d_in[2];
  const float* lw = (const float*)d_in[3];
  const float* lb = (const float*)d_in[4];
  const float* tkw = (const float*)d_in[5];
  const float* tkb = (const float*)d_in[6];
  const float* fe = (const float*)d_in[7];
  const float* gamma = (const float*)d_in[8];
  const float* beta = (const float*)d_in[9];
  const float* ow = (const float*)d_in[10];
  const float* obias = (const float*)d_in[11];
  float* out = (float*)d_out;

  float* ws = (float*)d_ws;
  float* cos_tab = ws;                                  // 3136 f
  float* wexp = cos_tab + HW_;                          // 602112 f
  float* zb = wexp + CHW_;                              // 38535168 f
  unsigned short* lwT = (unsigned short*)(zb + (size_t)B_ * CHW_);  // 73728 u16
  unsigned short* owT = lwT + 384 * C_;                 // 36864 u16
  unsigned short* yT = owT + C_ * C_;                   // 38535168 u16
  float* y = out;                                       // d_out: conv-out, then xp, then spectral

  hipLaunchKernelGGL(k_tables, dim3(13), dim3(256), 0, stream, cos_tab);
  hipLaunchKernelGGL(k_wexp, dim3(HW_ / 16), dim3(192), 0, stream, fe, tkw, tkb, wexp);
  hipLaunchKernelGGL(k_prep_w, dim3(432), dim3(256), 0, stream, lw, ow, lwT, owT);
  hipLaunchKernelGGL(k_conv, dim3((B_ * CHW_) / 256), dim3(256), 0, stream, x, dww, dwb, y);
  hipLaunchKernelGGL(k_t, dim3(HW_ / 64, B_), dim3(256), 0, stream, y, yT);
  hipLaunchKernelGGL(k_gemm1, dim3(75, B_), dim3(256), 0, stream, yT, lwT, lb, out, zb);
  hipLaunchKernelGGL(k_spec, dim3(B_ * C_), dim3(128), 0, stream, out, cos_tab, wexp, out);
  hipLaunchKernelGGL(k_ln2, dim3(HW_ / 64, B_), dim3(256), 0, stream, out, zb, gamma, beta,
                     owT, obias, out);
}

// Round 3
// 875.870 us; speedup vs baseline: 2.1612x; 1.2211x over previous
//
#include <hip/hip_runtime.h>
#include <math.h>

namespace {

constexpr int B_ = 64;
constexpr int C_ = 192;
constexpr int H_ = 56;
constexpr int W_ = 56;
constexpr int HW_ = H_ * W_;          // 3136
constexpr int CHW_ = C_ * HW_;        // 602112
constexpr float PI_F = 3.14159265358979323846f;

typedef __attribute__((ext_vector_type(8))) short short8;
typedef __attribute__((ext_vector_type(4))) float f32x4;

__device__ inline unsigned short f2bf(float f) {
  union { float f; unsigned u; } v{f};
  unsigned r = v.u + 0x7FFFu + ((v.u >> 16) & 1u);
  return (unsigned short)(r >> 16);
}

// XOR swizzle for [row][c] bf16 tiles, row stride 200 elems (16B granular)
__device__ inline int swz(int row) { return ((row >> 1) & 7) << 3; }

// ---------------------------------------------------------------------------
// K0: DCT-II basis table
// ---------------------------------------------------------------------------
__global__ void k_tables(float* __restrict__ cos_tab) {
  int i = blockIdx.x * 256 + threadIdx.x;
  if (i >= HW_) return;
  int n = i / W_;
  int x = i - n * W_;
  float wx = ((float)x + 0.5f) / 56.0f;
  float v = cosf(((float)n * wx) * PI_F) * 0.18898223650461362f;
  if (n == 0) v *= 0.7071067811865476f;
  cos_tab[i] = v;
}

// ---------------------------------------------------------------------------
// K_wexp: wexp[c][hw] = exp(-relu(fe@tok_w+tok_b) * (n^2+m^2))
// ---------------------------------------------------------------------------
__global__ __launch_bounds__(192) void k_wexp(const float* __restrict__ fe,
                                              const float* __restrict__ tkw,
                                              const float* __restrict__ tkb,
                                              float* __restrict__ wexp) {
  __shared__ float sfe[16][C_];
  int hw0 = blockIdx.x * 16;
  int t = threadIdx.x;
  for (int p = 0; p < 16; ++p) sfe[p][t] = fe[(size_t)(hw0 + p) * C_ + t];
  __syncthreads();
  float acc[16];
#pragma unroll
  for (int p = 0; p < 16; ++p) acc[p] = 0.f;
  for (int i = 0; i < C_; ++i) {
    float wv = tkw[i * C_ + t];
#pragma unroll
    for (int p = 0; p < 16; ++p) acc[p] = fmaf(sfe[p][i], wv, acc[p]);
  }
  float bias = tkb[t];
  const float step = PI_F / 56.0f;
#pragma unroll
  for (int p = 0; p < 16; ++p) {
    int hw = hw0 + p;
    int hh = hw / W_;
    int ww = hw - hh * W_;
    float nh = step * (float)hh;
    float nm = step * (float)ww;
    float a = nh * nh + nm * nm;
    float k = fmaxf(acc[p] + bias, 0.0f);
    wexp[(size_t)t * HW_ + hw] = expf(-k * a);
  }
}

// ---------------------------------------------------------------------------
// K_prep_w: lwT[j][c] = bf16(lin_w[c][j]), owT[j][c] = bf16(out_w[c][j])
// ---------------------------------------------------------------------------
__global__ __launch_bounds__(256) void k_prep_w(const float* __restrict__ lw,
                                                const float* __restrict__ ow,
                                                unsigned short* __restrict__ lwT,
                                                unsigned short* __restrict__ owT) {
  int i = blockIdx.x * 256 + threadIdx.x;
  if (i < 384 * 192) {
    int j = i / 192, c = i - j * 192;
    lwT[i] = f2bf(lw[c * 384 + j]);
  } else if (i < 384 * 192 + 192 * 192) {
    int k = i - 384 * 192;
    int j = k / 192, c = k - j * 192;
    owT[k] = f2bf(ow[c * 192 + j]);
  }
}

// ---------------------------------------------------------------------------
// K1: fused depthwise 3x3 conv + bias + transpose-to-bf16.
// Block = (64-pos tile, batch). Wave cr owns contiguous c in [48cr,48cr+48).
// Weights/bias are wave-uniform (scalar loads); boundary masks per-thread const.
// ---------------------------------------------------------------------------
__global__ __launch_bounds__(256) void k_convt(const float* __restrict__ x,
                                               const float* __restrict__ dww,
                                               const float* __restrict__ dwb,
                                               unsigned short* __restrict__ yT) {
  __shared__ unsigned short t[64 * 200];
  int b = blockIdx.y, pt = blockIdx.x;
  int tid = threadIdx.x;
  int p = tid & 63, cr = tid >> 6;
  int pos = pt * 64 + p;
  int h = pos / 56, w = pos - h * 56;
  bool hn = h > 0, hp = h < 55, wn = w > 0, wq = w < 55;
  const float* xb = x + (size_t)b * CHW_ + pos;
#pragma unroll
  for (int q = 0; q < 6; ++q) {
    short8 vv;
#pragma unroll
    for (int e = 0; e < 8; ++e) {
      int c = 48 * cr + 8 * q + e;
      const float* xc = xb + (size_t)c * HW_;
      const float* w9 = dww + c * 9;
      float a = dwb[c];
      if (hn) {
        if (wn) a = fmaf(xc[-57], w9[0], a);
        a = fmaf(xc[-56], w9[1], a);
        if (wq) a = fmaf(xc[-55], w9[2], a);
      }
      if (wn) a = fmaf(xc[-1], w9[3], a);
      a = fmaf(xc[0], w9[4], a);
      if (wq) a = fmaf(xc[1], w9[5], a);
      if (hp) {
        if (wn) a = fmaf(xc[55], w9[6], a);
        a = fmaf(xc[56], w9[7], a);
        if (wq) a = fmaf(xc[57], w9[8], a);
      }
      vv[e] = (short)f2bf(a);
    }
    *(short8*)&t[p * 200 + ((48 * cr + 8 * q) ^ swz(p))] = vv;
  }
  __syncthreads();
  unsigned short* o = yT + ((size_t)b * HW_ + pt * 64) * C_;
#pragma unroll
  for (int q = 0; q < 6; ++q) {
    int idx = q * 256 + tid;          // < 1536 = 64 pos x 24 blocks
    int pp = idx / 24, cb = idx % 24;
    short8 v = *(const short8*)&t[pp * 200 + ((cb * 8) ^ swz(pp))];
    *(short8*)&o[(size_t)idx * 8] = v;
  }
}

// ---------------------------------------------------------------------------
// K2: GEMM1 via MFMA bf16.  D[j 384][pos 3136] = lwT[j][c] * yT[pos][c]^T
// ---------------------------------------------------------------------------
__global__ __launch_bounds__(256) void k_gemm1(const unsigned short* __restrict__ yT,
                                               const unsigned short* __restrict__ lwT,
                                               const float* __restrict__ lb,
                                               float* __restrict__ xp,
                                               float* __restrict__ zb) {
  constexpr int LD = 40;
  __shared__ unsigned short sA[128 * LD];
  __shared__ unsigned short sY[128 * LD];
  int b = blockIdx.y;
  int bx = blockIdx.x;                // 75 -> bijective XCD swizzle (q=9,r=3)
  int xcd = bx & 7, o8 = bx >> 3;
  int lg = (xcd < 3 ? xcd * 10 : 30 + (xcd - 3) * 9) + o8;
  int pt = lg / 3, jt = lg % 3;
  int pos0 = pt * 128, j0 = jt * 128;
  int tid = threadIdx.x, lane = tid & 63, wv = tid >> 6;
  int wm = wv & 1, wn = wv >> 1;

  int row0 = tid >> 2, row1 = 64 + (tid >> 2), cb = (tid & 3) * 8;
  const unsigned short* a0 = lwT + (size_t)(j0 + row0) * C_ + cb;
  const unsigned short* a1 = lwT + (size_t)(j0 + row1) * C_ + cb;
  int pr0 = pos0 + row0; if (pr0 > HW_ - 1) pr0 = HW_ - 1;
  int pr1 = pos0 + row1; if (pr1 > HW_ - 1) pr1 = HW_ - 1;
  const unsigned short* b0 = yT + ((size_t)b * HW_ + pr0) * C_ + cb;
  const unsigned short* b1 = yT + ((size_t)b * HW_ + pr1) * C_ + cb;
  int d0 = row0 * LD + cb, d1 = row1 * LD + cb;

  f32x4 acc[4][4] = {};
  for (int kk = 0; kk < C_; kk += 32) {
    short8 va0 = *(const short8*)(a0 + kk);
    short8 va1 = *(const short8*)(a1 + kk);
    short8 vb0 = *(const short8*)(b0 + kk);
    short8 vb1 = *(const short8*)(b1 + kk);
    if (kk) __syncthreads();
    *(short8*)&sA[d0] = va0;
    *(short8*)&sA[d1] = va1;
    *(short8*)&sY[d0] = vb0;
    *(short8*)&sY[d1] = vb1;
    __syncthreads();
    int ra = (wm * 64 + (lane & 15)) * LD + (lane >> 4) * 8;
    int rb = (wn * 64 + (lane & 15)) * LD + (lane >> 4) * 8;
    short8 af[4], bf[4];
#pragma unroll
    for (int m = 0; m < 4; ++m) af[m] = *(const short8*)&sA[ra + m * 16 * LD];
#pragma unroll
    for (int n = 0; n < 4; ++n) bf[n] = *(const short8*)&sY[rb + n * 16 * LD];
#pragma unroll
    for (int m = 0; m < 4; ++m)
#pragma unroll
      for (int n = 0; n < 4; ++n)
        acc[m][n] = __builtin_amdgcn_mfma_f32_16x16x32_bf16(af[m], bf[n], acc[m][n], 0, 0, 0);
  }

#pragma unroll
  for (int m = 0; m < 4; ++m) {
    int jb = j0 + wm * 64 + m * 16 + (lane >> 4) * 4;
#pragma unroll
    for (int r = 0; r < 4; ++r) {
      int jg = jb + r;
      float bias = lb[jg];
      float* base = (jg < C_) ? (xp + ((size_t)b * C_ + jg) * HW_)
                              : (zb + ((size_t)b * C_ + (jg - C_)) * HW_);
#pragma unroll
      for (int n = 0; n < 4; ++n) {
        int pos = pos0 + wn * 64 + n * 16 + (lane & 15);
        if (pos < HW_) base[pos] = acc[m][n][r] + bias;
      }
    }
  }
}

// ---------------------------------------------------------------------------
// K4: spectral sandwich per (b,c) plane (fp32; in-place on d_out)
// ---------------------------------------------------------------------------
__global__ __launch_bounds__(128) void k_spec(const float* xp,
                                              const float* __restrict__ cos_tab,
                                              const float* __restrict__ wexp,
                                              float* sout) {
  constexpr int LDP = 60;
  __shared__ float scos[56 * LDP];
  __shared__ float bA[56 * LDP];
  __shared__ float bB[56 * LDP];
  const int bc = blockIdx.x;
  const int c = bc % C_;
  const float* P = xp + (size_t)bc * HW_;
  float* S = sout + (size_t)bc * HW_;
  const float* __restrict__ wx = wexp + (size_t)c * HW_;
  const int tid = threadIdx.x;
  for (int e = tid; e < HW_; e += 128) {
    int r = e / 56, q = e - r * 56;
    scos[r * LDP + q] = cos_tab[e];
    bA[r * LDP + q] = P[e];
  }
  __syncthreads();
  const bool act = tid < 98;
  const int i0 = (tid / 7) * 4;
  const int j0 = (tid % 7) * 8;
  float acc[4][8];

  if (act) {
#pragma unroll
    for (int i = 0; i < 4; ++i)
#pragma unroll
      for (int j = 0; j < 8; ++j) acc[i][j] = 0.f;
    for (int h = 0; h < 56; ++h) {
      float aa[4];
#pragma unroll
      for (int i = 0; i < 4; ++i) aa[i] = scos[(i0 + i) * LDP + h];
      float4 p0 = *(const float4*)&bA[h * LDP + j0];
      float4 p1 = *(const float4*)&bA[h * LDP + j0 + 4];
      const float pv[8] = {p0.x, p0.y, p0.z, p0.w, p1.x, p1.y, p1.z, p1.w};
#pragma unroll
      for (int i = 0; i < 4; ++i)
#pragma unroll
        for (int j = 0; j < 8; ++j) acc[i][j] = fmaf(aa[i], pv[j], acc[i][j]);
    }
#pragma unroll
    for (int i = 0; i < 4; ++i) {
      float4 v0 = {acc[i][0], acc[i][1], acc[i][2], acc[i][3]};
      float4 v1 = {acc[i][4], acc[i][5], acc[i][6], acc[i][7]};
      *(float4*)&bB[(i0 + i) * LDP + j0] = v0;
      *(float4*)&bB[(i0 + i) * LDP + j0 + 4] = v1;
    }
  }
  __syncthreads();

  if (act) {
#pragma unroll
    for (int i = 0; i < 4; ++i)
#pragma unroll
      for (int j = 0; j < 8; ++j) acc[i][j] = 0.f;
    for (int k = 0; k < 56; k += 4) {
      float4 t0 = *(const float4*)&bB[(i0 + 0) * LDP + k];
      float4 t1 = *(const float4*)&bB[(i0 + 1) * LDP + k];
      float4 t2 = *(const float4*)&bB[(i0 + 2) * LDP + k];
      float4 t3 = *(const float4*)&bB[(i0 + 3) * LDP + k];
#pragma unroll
      for (int j = 0; j < 8; ++j) {
        float4 cv = *(const float4*)&scos[(j0 + j) * LDP + k];
        acc[0][j] = fmaf(t0.x, cv.x, fmaf(t0.y, cv.y, fmaf(t0.z, cv.z, fmaf(t0.w, cv.w, acc[0][j]))));
        acc[1][j] = fmaf(t1.x, cv.x, fmaf(t1.y, cv.y, fmaf(t1.z, cv.z, fmaf(t1.w, cv.w, acc[1][j]))));
        acc[2][j] = fmaf(t2.x, cv.x, fmaf(t2.y, cv.y, fmaf(t2.z, cv.z, fmaf(t2.w, cv.w, acc[2][j]))));
        acc[3][j] = fmaf(t3.x, cv.x, fmaf(t3.y, cv.y, fmaf(t3.z, cv.z, fmaf(t3.w, cv.w, acc[3][j]))));
      }
    }
#pragma unroll
    for (int i = 0; i < 4; ++i) {
      float4 w0 = *(const float4*)&wx[(i0 + i) * 56 + j0];
      float4 w1 = *(const float4*)&wx[(i0 + i) * 56 + j0 + 4];
      float4 v0 = {acc[i][0] * w0.x, acc[i][1] * w0.y, acc[i][2] * w0.z, acc[i][3] * w0.w};
      float4 v1 = {acc[i][4] * w1.x, acc[i][5] * w1.y, acc[i][6] * w1.z, acc[i][7] * w1.w};
      *(float4*)&bA[(i0 + i) * LDP + j0] = v0;
      *(float4*)&bA[(i0 + i) * LDP + j0 + 4] = v1;
    }
  }
  __syncthreads();

  if (act) {
#pragma unroll
    for (int i = 0; i < 4; ++i)
#pragma unroll
      for (int j = 0; j < 8; ++j) acc[i][j] = 0.f;
    for (int k = 0; k < 56; ++k) {
      float4 av = *(const float4*)&scos[k * LDP + i0];
      float4 g0 = *(const float4*)&bA[k * LDP + j0];
      float4 g1 = *(const float4*)&bA[k * LDP + j0 + 4];
      const float aa[4] = {av.x, av.y, av.z, av.w};
      const float gv[8] = {g0.x, g0.y, g0.z, g0.w, g1.x, g1.y, g1.z, g1.w};
#pragma unroll
      for (int i = 0; i < 4; ++i)
#pragma unroll
        for (int j = 0; j < 8; ++j) acc[i][j] = fmaf(aa[i], gv[j], acc[i][j]);
    }
#pragma unroll
    for (int i = 0; i < 4; ++i) {
      float4 v0 = {acc[i][0], acc[i][1], acc[i][2], acc[i][3]};
      float4 v1 = {acc[i][4], acc[i][5], acc[i][6], acc[i][7]};
      *(float4*)&bB[(i0 + i) * LDP + j0] = v0;
      *(float4*)&bB[(i0 + i) * LDP + j0 + 4] = v1;
    }
  }
  __syncthreads();

  if (act) {
#pragma unroll
    for (int i = 0; i < 4; ++i)
#pragma unroll
      for (int j = 0; j < 8; ++j) acc[i][j] = 0.f;
    for (int k = 0; k < 56; ++k) {
      float aa[4];
#pragma unroll
      for (int i = 0; i < 4; ++i) aa[i] = bB[(i0 + i) * LDP + k];
      float4 c0 = *(const float4*)&scos[k * LDP + j0];
      float4 c1 = *(const float4*)&scos[k * LDP + j0 + 4];
      const float cv[8] = {c0.x, c0.y, c0.z, c0.w, c1.x, c1.y, c1.z, c1.w};
#pragma unroll
      for (int i = 0; i < 4; ++i)
#pragma unroll
        for (int j = 0; j < 8; ++j) acc[i][j] = fmaf(aa[i], cv[j], acc[i][j]);
    }
#pragma unroll
    for (int i = 0; i < 4; ++i) {
      float4 v0 = {acc[i][0], acc[i][1], acc[i][2], acc[i][3]};
      float4 v1 = {acc[i][4], acc[i][5], acc[i][6], acc[i][7]};
      *(float4*)&S[(i0 + i) * 56 + j0] = v0;
      *(float4*)&S[(i0 + i) * 56 + j0 + 4] = v1;
    }
  }
}

// ---------------------------------------------------------------------------
// K5: LayerNorm -> silu-gate -> GEMM2 via MFMA bf16.
// Wave cr owns contiguous c in [48cr,48cr+48) -> vectorized act writes.
// A-fragments (owT) read directly from global (L2-resident, 72KB).
// s aliases out: all s-reads precede the epilogue stores (in-block safe).
// ---------------------------------------------------------------------------
__global__ __launch_bounds__(256) void k_ln2(const float* s,
                                             const float* __restrict__ z,
                                             const float* __restrict__ gamma,
                                             const float* __restrict__ beta,
                                             const unsigned short* __restrict__ owT,
                                             const float* __restrict__ ob,
                                             float* out) {
  __shared__ unsigned short act[64 * 200];
  __shared__ float red[8][64];
  __shared__ float smu[64], srs[64];
  int b = blockIdx.y, pt = blockIdx.x;
  int tid = threadIdx.x, lane = tid & 63, wv = tid >> 6;
  int p = lane, cr = wv;
  const float* sp = s + (size_t)b * CHW_ + (size_t)(48 * cr) * HW_ + pt * 64 + p;
  const float* zp = z + (size_t)b * CHW_ + (size_t)(48 * cr) * HW_ + pt * 64 + p;
  float sv[48];
  float sum = 0.f, sq = 0.f;
#pragma unroll
  for (int i = 0; i < 48; ++i) {
    float v = sp[(size_t)i * HW_];
    sv[i] = v;
    sum += v;
    sq = fmaf(v, v, sq);
  }
  red[cr][p] = sum;
  red[4 + cr][p] = sq;
  __syncthreads();
  if (tid < 64) {
    float s1 = red[0][tid] + red[1][tid] + red[2][tid] + red[3][tid];
    float s2 = red[4][tid] + red[5][tid] + red[6][tid] + red[7][tid];
    float mu = s1 * (1.0f / 192.0f);
    float var = s2 * (1.0f / 192.0f) - mu * mu;
    smu[tid] = mu;
    srs[tid] = rsqrtf(var + 1e-5f);
  }
  __syncthreads();
  float mu = smu[p], rs = srs[p];
#pragma unroll
  for (int q = 0; q < 6; ++q) {
    short8 vv;
#pragma unroll
    for (int e = 0; e < 8; ++e) {
      int i = 8 * q + e;
      int c = 48 * cr + i;
      float v = (sv[i] - mu) * rs * gamma[c] + beta[c];
      float zz = zp[(size_t)i * HW_];
      v *= zz / (1.0f + expf(-zz));
      vv[e] = (short)f2bf(v);
    }
    *(short8*)&act[p * 200 + ((48 * cr + 8 * q) ^ swz(p))] = vv;
  }
  __syncthreads();

  f32x4 acc[3][4] = {};
  const unsigned short* ap = owT + (size_t)(wv * 48 + (lane & 15)) * C_ + (lane >> 4) * 8;
#pragma unroll
  for (int kk = 0; kk < C_; kk += 32) {
    short8 af[3], bf[4];
#pragma unroll
    for (int m = 0; m < 3; ++m) af[m] = *(const short8*)(ap + m * 16 * C_ + kk);
#pragma unroll
    for (int n = 0; n < 4; ++n) {
      int row = (lane & 15) + 16 * n;
      int co = (kk + (lane >> 4) * 8) ^ swz(row);
      bf[n] = *(const short8*)&act[row * 200 + co];
    }
#pragma unroll
    for (int m = 0; m < 3; ++m)
#pragma unroll
      for (int n = 0; n < 4; ++n)
        acc[m][n] = __builtin_amdgcn_mfma_f32_16x16x32_bf16(af[m], bf[n], acc[m][n], 0, 0, 0);
  }

  float* op = out + (size_t)b * CHW_ + pt * 64;
#pragma unroll
  for (int m = 0; m < 3; ++m) {
    int jb = wv * 48 + m * 16 + (lane >> 4) * 4;
#pragma unroll
    for (int r = 0; r < 4; ++r) {
      int j = jb + r;
      float bias = ob[j];
#pragma unroll
      for (int n = 0; n < 4; ++n) {
        int pos = n * 16 + (lane & 15);
        op[(size_t)j * HW_ + pos] = acc[m][n][r] + bias;
      }
    }
  }
}

}  // namespace

extern "C" void kernel_launch(void* const* d_in, const int* in_sizes, int n_in,
                              void* d_out, int out_size, void* d_ws, size_t ws_size,
                              hipStream_t stream) {
  const float* x = (const float*)d_in[0];
  const float* dww = (const float*)d_in[1];
  const float* dwb = (const float*)d_in[2];
  const float* lw = (const float*)d_in[3];
  const float* lb = (const float*)d_in[4];
  const float* tkw = (const float*)d_in[5];
  const float* tkb = (const float*)d_in[6];
  const float* fe = (const float*)d_in[7];
  const float* gamma = (const float*)d_in[8];
  const float* beta = (const float*)d_in[9];
  const float* ow = (const float*)d_in[10];
  const float* obias = (const float*)d_in[11];
  float* out = (float*)d_out;

  float* ws = (float*)d_ws;
  float* cos_tab = ws;                                  // 3136 f
  float* wexp = cos_tab + HW_;                          // 602112 f
  float* zb = wexp + CHW_;                              // 38535168 f
  unsigned short* lwT = (unsigned short*)(zb + (size_t)B_ * CHW_);  // 73728 u16
  unsigned short* owT = lwT + 384 * C_;                 // 36864 u16
  unsigned short* yT = owT + C_ * C_;                   // 38535168 u16

  hipLaunchKernelGGL(k_tables, dim3(13), dim3(256), 0, stream, cos_tab);
  hipLaunchKernelGGL(k_wexp, dim3(HW_ / 16), dim3(192), 0, stream, fe, tkw, tkb, wexp);
  hipLaunchKernelGGL(k_prep_w, dim3(432), dim3(256), 0, stream, lw, ow, lwT, owT);
  hipLaunchKernelGGL(k_convt, dim3(HW_ / 64, B_), dim3(256), 0, stream, x, dww, dwb, yT);
  hipLaunchKernelGGL(k_gemm1, dim3(75, B_), dim3(256), 0, stream, yT, lwT, lb, out, zb);
  hipLaunchKernelGGL(k_spec, dim3(B_ * C_), dim3(128), 0, stream, out, cos_tab, wexp, out);
  hipLaunchKernelGGL(k_ln2, dim3(HW_ / 64, B_), dim3(256), 0, stream, out, zb, gamma, beta,
                     owT, obias, out);
}

// Round 5
// 691.369 us; speedup vs baseline: 2.7380x; 1.2669x over previous
//
#include <hip/hip_runtime.h>
#include <math.h>

namespace {

constexpr int B_ = 64;
constexpr int C_ = 192;
constexpr int H_ = 56;
constexpr int W_ = 56;
constexpr int HW_ = H_ * W_;          // 3136
constexpr int CHW_ = C_ * HW_;        // 602112
constexpr float PI_F = 3.14159265358979323846f;

typedef __attribute__((ext_vector_type(8))) short short8;
typedef __attribute__((ext_vector_type(4))) float f32x4;

__device__ inline unsigned short f2bf(float f) {
  union { float f; unsigned u; } v{f};
  unsigned r = v.u + 0x7FFFu + ((v.u >> 16) & 1u);
  return (unsigned short)(r >> 16);
}

// XOR swizzle for [row][c] bf16 tiles, row stride 200 elems (16B granular)
__device__ inline int swz(int row) { return ((row >> 1) & 7) << 3; }

// ---------------------------------------------------------------------------
// K0: DCT-II basis table
// ---------------------------------------------------------------------------
__global__ void k_tables(float* __restrict__ cos_tab) {
  int i = blockIdx.x * 256 + threadIdx.x;
  if (i >= HW_) return;
  int n = i / W_;
  int x = i - n * W_;
  float wx = ((float)x + 0.5f) / 56.0f;
  float v = cosf(((float)n * wx) * PI_F) * 0.18898223650461362f;
  if (n == 0) v *= 0.7071067811865476f;
  cos_tab[i] = v;
}

// ---------------------------------------------------------------------------
// K_wexp: wexp[c][hw] = exp(-relu(fe@tok_w+tok_b) * (n^2+m^2))
// ---------------------------------------------------------------------------
__global__ __launch_bounds__(192) void k_wexp(const float* __restrict__ fe,
                                              const float* __restrict__ tkw,
                                              const float* __restrict__ tkb,
                                              float* __restrict__ wexp) {
  __shared__ float sfe[16][C_];
  int hw0 = blockIdx.x * 16;
  int t = threadIdx.x;
  for (int p = 0; p < 16; ++p) sfe[p][t] = fe[(size_t)(hw0 + p) * C_ + t];
  __syncthreads();
  float acc[16];
#pragma unroll
  for (int p = 0; p < 16; ++p) acc[p] = 0.f;
  for (int i = 0; i < C_; ++i) {
    float wv = tkw[i * C_ + t];
#pragma unroll
    for (int p = 0; p < 16; ++p) acc[p] = fmaf(sfe[p][i], wv, acc[p]);
  }
  float bias = tkb[t];
  const float step = PI_F / 56.0f;
#pragma unroll
  for (int p = 0; p < 16; ++p) {
    int hw = hw0 + p;
    int hh = hw / W_;
    int ww = hw - hh * W_;
    float nh = step * (float)hh;
    float nm = step * (float)ww;
    float a = nh * nh + nm * nm;
    float k = fmaxf(acc[p] + bias, 0.0f);
    wexp[(size_t)t * HW_ + hw] = expf(-k * a);
  }
}

// ---------------------------------------------------------------------------
// K_prep_w: lwT[j][c] = bf16(lin_w[c][j]), owT[j][c] = bf16(out_w[c][j])
// ---------------------------------------------------------------------------
__global__ __launch_bounds__(256) void k_prep_w(const float* __restrict__ lw,
                                                const float* __restrict__ ow,
                                                unsigned short* __restrict__ lwT,
                                                unsigned short* __restrict__ owT) {
  int i = blockIdx.x * 256 + threadIdx.x;
  if (i < 384 * 192) {
    int j = i / 192, c = i - j * 192;
    lwT[i] = f2bf(lw[c * 384 + j]);
  } else if (i < 384 * 192 + 192 * 192) {
    int k = i - 384 * 192;
    int j = k / 192, c = k - j * 192;
    owT[k] = f2bf(ow[c * 192 + j]);
  }
}

// ---------------------------------------------------------------------------
// K1: fused depthwise 3x3 conv + bias + transpose-to-bf16 (v2).
// 512 thr: wave cr in [0,8) owns contiguous c in [24cr,24cr+24).
// Branch-free: clamped tap offsets + 0/1 mask multiply -> loads batch per
// channel (9 back-to-back global_load_dword), one latency wait per channel.
// ---------------------------------------------------------------------------
__global__ __launch_bounds__(512) void k_convt(const float* __restrict__ x,
                                               const float* __restrict__ dww,
                                               const float* __restrict__ dwb,
                                               unsigned short* __restrict__ yT) {
  __shared__ unsigned short t[64 * 200];
  int b = blockIdx.y, pt = blockIdx.x;
  int tid = threadIdx.x;
  int p = tid & 63, cr = tid >> 6;
  int pos = pt * 64 + p;
  int h = pos / 56, w = pos - h * 56;
  bool hn = h > 0, hp = h < 55, wn = w > 0, wq = w < 55;
  int o00 = (hn && wn) ? -57 : 0, o01 = hn ? -56 : 0, o02 = (hn && wq) ? -55 : 0;
  int o10 = wn ? -1 : 0, o12 = wq ? 1 : 0;
  int o20 = (hp && wn) ? 55 : 0, o21 = hp ? 56 : 0, o22 = (hp && wq) ? 57 : 0;
  float f00 = (hn && wn) ? 1.f : 0.f, f01 = hn ? 1.f : 0.f, f02 = (hn && wq) ? 1.f : 0.f;
  float f10 = wn ? 1.f : 0.f, f12 = wq ? 1.f : 0.f;
  float f20 = (hp && wn) ? 1.f : 0.f, f21 = hp ? 1.f : 0.f, f22 = (hp && wq) ? 1.f : 0.f;
  const float* xb = x + (size_t)b * CHW_ + pos;
#pragma unroll
  for (int q = 0; q < 3; ++q) {
    short8 vv;
#pragma unroll
    for (int e = 0; e < 8; ++e) {
      int c = cr * 24 + q * 8 + e;
      const float* xc = xb + (size_t)c * HW_;
      const float* w9 = dww + c * 9;
      float v0 = xc[o00], v1 = xc[o01], v2 = xc[o02];
      float v3 = xc[o10], v4 = xc[0], v5 = xc[o12];
      float v6 = xc[o20], v7 = xc[o21], v8 = xc[o22];
      float a = dwb[c];
      a = fmaf(v0 * f00, w9[0], a);
      a = fmaf(v1 * f01, w9[1], a);
      a = fmaf(v2 * f02, w9[2], a);
      a = fmaf(v3 * f10, w9[3], a);
      a = fmaf(v4, w9[4], a);
      a = fmaf(v5 * f12, w9[5], a);
      a = fmaf(v6 * f20, w9[6], a);
      a = fmaf(v7 * f21, w9[7], a);
      a = fmaf(v8 * f22, w9[8], a);
      vv[e] = (short)f2bf(a);
    }
    *(short8*)&t[p * 200 + ((cr * 24 + q * 8) ^ swz(p))] = vv;
  }
  __syncthreads();
  unsigned short* o = yT + ((size_t)b * HW_ + pt * 64) * C_;
#pragma unroll
  for (int q = 0; q < 3; ++q) {
    int idx = q * 512 + tid;          // < 1536 = 64 pos x 24 chunks
    int pp = idx / 24, cb = idx - pp * 24;
    short8 v = *(const short8*)&t[pp * 200 + ((cb * 8) ^ swz(pp))];
    *(short8*)&o[(size_t)idx * 8] = v;
  }
}

// ---------------------------------------------------------------------------
// K2: GEMM1 via MFMA bf16.  D[j 384][pos 3136] = lwT[j][c] * yT[pos][c]^T
// ---------------------------------------------------------------------------
__global__ __launch_bounds__(256) void k_gemm1(const unsigned short* __restrict__ yT,
                                               const unsigned short* __restrict__ lwT,
                                               const float* __restrict__ lb,
                                               float* __restrict__ xp,
                                               float* __restrict__ zb) {
  constexpr int LD = 40;
  __shared__ unsigned short sA[128 * LD];
  __shared__ unsigned short sY[128 * LD];
  int b = blockIdx.y;
  int bx = blockIdx.x;                // 75 -> bijective XCD swizzle (q=9,r=3)
  int xcd = bx & 7, o8 = bx >> 3;
  int lg = (xcd < 3 ? xcd * 10 : 30 + (xcd - 3) * 9) + o8;
  int pt = lg / 3, jt = lg % 3;
  int pos0 = pt * 128, j0 = jt * 128;
  int tid = threadIdx.x, lane = tid & 63, wv = tid >> 6;
  int wm = wv & 1, wn = wv >> 1;

  int row0 = tid >> 2, row1 = 64 + (tid >> 2), cb = (tid & 3) * 8;
  const unsigned short* a0 = lwT + (size_t)(j0 + row0) * C_ + cb;
  const unsigned short* a1 = lwT + (size_t)(j0 + row1) * C_ + cb;
  int pr0 = pos0 + row0; if (pr0 > HW_ - 1) pr0 = HW_ - 1;
  int pr1 = pos0 + row1; if (pr1 > HW_ - 1) pr1 = HW_ - 1;
  const unsigned short* b0 = yT + ((size_t)b * HW_ + pr0) * C_ + cb;
  const unsigned short* b1 = yT + ((size_t)b * HW_ + pr1) * C_ + cb;
  int d0 = row0 * LD + cb, d1 = row1 * LD + cb;

  f32x4 acc[4][4] = {};
  for (int kk = 0; kk < C_; kk += 32) {
    short8 va0 = *(const short8*)(a0 + kk);
    short8 va1 = *(const short8*)(a1 + kk);
    short8 vb0 = *(const short8*)(b0 + kk);
    short8 vb1 = *(const short8*)(b1 + kk);
    if (kk) __syncthreads();
    *(short8*)&sA[d0] = va0;
    *(short8*)&sA[d1] = va1;
    *(short8*)&sY[d0] = vb0;
    *(short8*)&sY[d1] = vb1;
    __syncthreads();
    int ra = (wm * 64 + (lane & 15)) * LD + (lane >> 4) * 8;
    int rb = (wn * 64 + (lane & 15)) * LD + (lane >> 4) * 8;
    short8 af[4], bf[4];
#pragma unroll
    for (int m = 0; m < 4; ++m) af[m] = *(const short8*)&sA[ra + m * 16 * LD];
#pragma unroll
    for (int n = 0; n < 4; ++n) bf[n] = *(const short8*)&sY[rb + n * 16 * LD];
#pragma unroll
    for (int m = 0; m < 4; ++m)
#pragma unroll
      for (int n = 0; n < 4; ++n)
        acc[m][n] = __builtin_amdgcn_mfma_f32_16x16x32_bf16(af[m], bf[n], acc[m][n], 0, 0, 0);
  }

#pragma unroll
  for (int m = 0; m < 4; ++m) {
    int jb = j0 + wm * 64 + m * 16 + (lane >> 4) * 4;
#pragma unroll
    for (int r = 0; r < 4; ++r) {
      int jg = jb + r;
      float bias = lb[jg];
      float* base = (jg < C_) ? (xp + ((size_t)b * C_ + jg) * HW_)
                              : (zb + ((size_t)b * C_ + (jg - C_)) * HW_);
#pragma unroll
      for (int n = 0; n < 4; ++n) {
        int pos = pos0 + wn * 64 + n * 16 + (lane & 15);
        if (pos < HW_) base[pos] = acc[m][n][r] + bias;
      }
    }
  }
}

// ---------------------------------------------------------------------------
// K4: spectral sandwich per (b,c) plane (fp32; in-place on d_out)
// ---------------------------------------------------------------------------
__global__ __launch_bounds__(128) void k_spec(const float* xp,
                                              const float* __restrict__ cos_tab,
                                              const float* __restrict__ wexp,
                                              float* sout) {
  constexpr int LDP = 60;
  __shared__ float scos[56 * LDP];
  __shared__ float bA[56 * LDP];
  __shared__ float bB[56 * LDP];
  const int bc = blockIdx.x;
  const int c = bc % C_;
  const float* P = xp + (size_t)bc * HW_;
  float* S = sout + (size_t)bc * HW_;
  const float* __restrict__ wx = wexp + (size_t)c * HW_;
  const int tid = threadIdx.x;
  for (int e = tid; e < HW_; e += 128) {
    int r = e / 56, q = e - r * 56;
    scos[r * LDP + q] = cos_tab[e];
    bA[r * LDP + q] = P[e];
  }
  __syncthreads();
  const bool act = tid < 98;
  const int i0 = (tid / 7) * 4;
  const int j0 = (tid % 7) * 8;
  float acc[4][8];

  if (act) {
#pragma unroll
    for (int i = 0; i < 4; ++i)
#pragma unroll
      for (int j = 0; j < 8; ++j) acc[i][j] = 0.f;
    for (int h = 0; h < 56; ++h) {
      float aa[4];
#pragma unroll
      for (int i = 0; i < 4; ++i) aa[i] = scos[(i0 + i) * LDP + h];
      float4 p0 = *(const float4*)&bA[h * LDP + j0];
      float4 p1 = *(const float4*)&bA[h * LDP + j0 + 4];
      const float pv[8] = {p0.x, p0.y, p0.z, p0.w, p1.x, p1.y, p1.z, p1.w};
#pragma unroll
      for (int i = 0; i < 4; ++i)
#pragma unroll
        for (int j = 0; j < 8; ++j) acc[i][j] = fmaf(aa[i], pv[j], acc[i][j]);
    }
#pragma unroll
    for (int i = 0; i < 4; ++i) {
      float4 v0 = {acc[i][0], acc[i][1], acc[i][2], acc[i][3]};
      float4 v1 = {acc[i][4], acc[i][5], acc[i][6], acc[i][7]};
      *(float4*)&bB[(i0 + i) * LDP + j0] = v0;
      *(float4*)&bB[(i0 + i) * LDP + j0 + 4] = v1;
    }
  }
  __syncthreads();

  if (act) {
#pragma unroll
    for (int i = 0; i < 4; ++i)
#pragma unroll
      for (int j = 0; j < 8; ++j) acc[i][j] = 0.f;
    for (int k = 0; k < 56; k += 4) {
      float4 t0 = *(const float4*)&bB[(i0 + 0) * LDP + k];
      float4 t1 = *(const float4*)&bB[(i0 + 1) * LDP + k];
      float4 t2 = *(const float4*)&bB[(i0 + 2) * LDP + k];
      float4 t3 = *(const float4*)&bB[(i0 + 3) * LDP + k];
#pragma unroll
      for (int j = 0; j < 8; ++j) {
        float4 cv = *(const float4*)&scos[(j0 + j) * LDP + k];
        acc[0][j] = fmaf(t0.x, cv.x, fmaf(t0.y, cv.y, fmaf(t0.z, cv.z, fmaf(t0.w, cv.w, acc[0][j]))));
        acc[1][j] = fmaf(t1.x, cv.x, fmaf(t1.y, cv.y, fmaf(t1.z, cv.z, fmaf(t1.w, cv.w, acc[1][j]))));
        acc[2][j] = fmaf(t2.x, cv.x, fmaf(t2.y, cv.y, fmaf(t2.z, cv.z, fmaf(t2.w, cv.w, acc[2][j]))));
        acc[3][j] = fmaf(t3.x, cv.x, fmaf(t3.y, cv.y, fmaf(t3.z, cv.z, fmaf(t3.w, cv.w, acc[3][j]))));
      }
    }
#pragma unroll
    for (int i = 0; i < 4; ++i) {
      float4 w0 = *(const float4*)&wx[(i0 + i) * 56 + j0];
      float4 w1 = *(const float4*)&wx[(i0 + i) * 56 + j0 + 4];
      float4 v0 = {acc[i][0] * w0.x, acc[i][1] * w0.y, acc[i][2] * w0.z, acc[i][3] * w0.w};
      float4 v1 = {acc[i][4] * w1.x, acc[i][5] * w1.y, acc[i][6] * w1.z, acc[i][7] * w1.w};
      *(float4*)&bA[(i0 + i) * LDP + j0] = v0;
      *(float4*)&bA[(i0 + i) * LDP + j0 + 4] = v1;
    }
  }
  __syncthreads();

  if (act) {
#pragma unroll
    for (int i = 0; i < 4; ++i)
#pragma unroll
      for (int j = 0; j < 8; ++j) acc[i][j] = 0.f;
    for (int k = 0; k < 56; ++k) {
      float4 av = *(const float4*)&scos[k * LDP + i0];
      float4 g0 = *(const float4*)&bA[k * LDP + j0];
      float4 g1 = *(const float4*)&bA[k * LDP + j0 + 4];
      const float aa[4] = {av.x, av.y, av.z, av.w};
      const float gv[8] = {g0.x, g0.y, g0.z, g0.w, g1.x, g1.y, g1.z, g1.w};
#pragma unroll
      for (int i = 0; i < 4; ++i)
#pragma unroll
        for (int j = 0; j < 8; ++j) acc[i][j] = fmaf(aa[i], gv[j], acc[i][j]);
    }
#pragma unroll
    for (int i = 0; i < 4; ++i) {
      float4 v0 = {acc[i][0], acc[i][1], acc[i][2], acc[i][3]};
      float4 v1 = {acc[i][4], acc[i][5], acc[i][6], acc[i][7]};
      *(float4*)&bB[(i0 + i) * LDP + j0] = v0;
      *(float4*)&bB[(i0 + i) * LDP + j0 + 4] = v1;
    }
  }
  __syncthreads();

  if (act) {
#pragma unroll
    for (int i = 0; i < 4; ++i)
#pragma unroll
      for (int j = 0; j < 8; ++j) acc[i][j] = 0.f;
    for (int k = 0; k < 56; ++k) {
      float aa[4];
#pragma unroll
      for (int i = 0; i < 4; ++i) aa[i] = bB[(i0 + i) * LDP + k];
      float4 c0 = *(const float4*)&scos[k * LDP + j0];
      float4 c1 = *(const float4*)&scos[k * LDP + j0 + 4];
      const float cv[8] = {c0.x, c0.y, c0.z, c0.w, c1.x, c1.y, c1.z, c1.w};
#pragma unroll
      for (int i = 0; i < 4; ++i)
#pragma unroll
        for (int j = 0; j < 8; ++j) acc[i][j] = fmaf(aa[i], cv[j], acc[i][j]);
    }
#pragma unroll
    for (int i = 0; i < 4; ++i) {
      float4 v0 = {acc[i][0], acc[i][1], acc[i][2], acc[i][3]};
      float4 v1 = {acc[i][4], acc[i][5], acc[i][6], acc[i][7]};
      *(float4*)&S[(i0 + i) * 56 + j0] = v0;
      *(float4*)&S[(i0 + i) * 56 + j0 + 4] = v1;
    }
  }
}

// ---------------------------------------------------------------------------
// K5: LayerNorm -> silu-gate -> GEMM2 via MFMA bf16.
// ---------------------------------------------------------------------------
__global__ __launch_bounds__(256) void k_ln2(const float* s,
                                             const float* __restrict__ z,
                                             const float* __restrict__ gamma,
                                             const float* __restrict__ beta,
                                             const unsigned short* __restrict__ owT,
                                             const float* __restrict__ ob,
                                             float* out) {
  __shared__ unsigned short act[64 * 200];
  __shared__ float red[8][64];
  __shared__ float smu[64], srs[64];
  int b = blockIdx.y, pt = blockIdx.x;
  int tid = threadIdx.x, lane = tid & 63, wv = tid >> 6;
  int p = lane, cr = wv;
  const float* sp = s + (size_t)b * CHW_ + (size_t)(48 * cr) * HW_ + pt * 64 + p;
  const float* zp = z + (size_t)b * CHW_ + (size_t)(48 * cr) * HW_ + pt * 64 + p;
  float sv[48];
  float sum = 0.f, sq = 0.f;
#pragma unroll
  for (int i = 0; i < 48; ++i) {
    float v = sp[(size_t)i * HW_];
    sv[i] = v;
    sum += v;
    sq = fmaf(v, v, sq);
  }
  red[cr][p] = sum;
  red[4 + cr][p] = sq;
  __syncthreads();
  if (tid < 64) {
    float s1 = red[0][tid] + red[1][tid] + red[2][tid] + red[3][tid];
    float s2 = red[4][tid] + red[5][tid] + red[6][tid] + red[7][tid];
    float mu = s1 * (1.0f / 192.0f);
    float var = s2 * (1.0f / 192.0f) - mu * mu;
    smu[tid] = mu;
    srs[tid] = rsqrtf(var + 1e-5f);
  }
  __syncthreads();
  float mu = smu[p], rs = srs[p];
#pragma unroll
  for (int q = 0; q < 6; ++q) {
    short8 vv;
#pragma unroll
    for (int e = 0; e < 8; ++e) {
      int i = 8 * q + e;
      int c = 48 * cr + i;
      float v = (sv[i] - mu) * rs * gamma[c] + beta[c];
      float zz = zp[(size_t)i * HW_];
      v *= zz / (1.0f + expf(-zz));
      vv[e] = (short)f2bf(v);
    }
    *(short8*)&act[p * 200 + ((48 * cr + 8 * q) ^ swz(p))] = vv;
  }
  __syncthreads();

  f32x4 acc[3][4] = {};
  const unsigned short* ap = owT + (size_t)(wv * 48 + (lane & 15)) * C_ + (lane >> 4) * 8;
#pragma unroll
  for (int kk = 0; kk < C_; kk += 32) {
    short8 af[3], bf[4];
#pragma unroll
    for (int m = 0; m < 3; ++m) af[m] = *(const short8*)(ap + m * 16 * C_ + kk);
#pragma unroll
    for (int n = 0; n < 4; ++n) {
      int row = (lane & 15) + 16 * n;
      int co = (kk + (lane >> 4) * 8) ^ swz(row);
      bf[n] = *(const short8*)&act[row * 200 + co];
    }
#pragma unroll
    for (int m = 0; m < 3; ++m)
#pragma unroll
      for (int n = 0; n < 4; ++n)
        acc[m][n] = __builtin_amdgcn_mfma_f32_16x16x32_bf16(af[m], bf[n], acc[m][n], 0, 0, 0);
  }

  float* op = out + (size_t)b * CHW_ + pt * 64;
#pragma unroll
  for (int m = 0; m < 3; ++m) {
    int jb = wv * 48 + m * 16 + (lane >> 4) * 4;
#pragma unroll
    for (int r = 0; r < 4; ++r) {
      int j = jb + r;
      float bias = ob[j];
#pragma unroll
      for (int n = 0; n < 4; ++n) {
        int pos = n * 16 + (lane & 15);
        op[(size_t)j * HW_ + pos] = acc[m][n][r] + bias;
      }
    }
  }
}

}  // namespace

extern "C" void kernel_launch(void* const* d_in, const int* in_sizes, int n_in,
                              void* d_out, int out_size, void* d_ws, size_t ws_size,
                              hipStream_t stream) {
  const float* x = (const float*)d_in[0];
  const float* dww = (const float*)d_in[1];
  const float* dwb = (const float*)d_in[2];
  const float* lw = (const float*)d_in[3];
  const float* lb = (const float*)d_in[4];
  const float* tkw = (const float*)d_in[5];
  const float* tkb = (const float*)d_in[6];
  const float* fe = (const float*)d_in[7];
  const float* gamma = (const float*)d_in[8];
  const float* beta = (const float*)d_in[9];
  const float* ow = (const float*)d_in[10];
  const float* obias = (const float*)d_in[11];
  float* out = (float*)d_out;

  float* ws = (float*)d_ws;
  float* cos_tab = ws;                                  // 3136 f
  float* wexp = cos_tab + HW_;                          // 602112 f
  float* zb = wexp + CHW_;                              // 38535168 f
  unsigned short* lwT = (unsigned short*)(zb + (size_t)B_ * CHW_);  // 73728 u16
  unsigned short* owT = lwT + 384 * C_;                 // 36864 u16
  unsigned short* yT = owT + C_ * C_;                   // 38535168 u16

  hipLaunchKernelGGL(k_tables, dim3(13), dim3(256), 0, stream, cos_tab);
  hipLaunchKernelGGL(k_wexp, dim3(HW_ / 16), dim3(192), 0, stream, fe, tkw, tkb, wexp);
  hipLaunchKernelGGL(k_prep_w, dim3(432), dim3(256), 0, stream, lw, ow, lwT, owT);
  hipLaunchKernelGGL(k_convt, dim3(HW_ / 64, B_), dim3(512), 0, stream, x, dww, dwb, yT);
  hipLaunchKernelGGL(k_gemm1, dim3(75, B_), dim3(256), 0, stream, yT, lwT, lb, out, zb);
  hipLaunchKernelGGL(k_spec, dim3(B_ * C_), dim3(128), 0, stream, out, cos_tab, wexp, out);
  hipLaunchKernelGGL(k_ln2, dim3(HW_ / 64, B_), dim3(256), 0, stream, out, zb, gamma, beta,
                     owT, obias, out);
}

// Round 6
// 572.442 us; speedup vs baseline: 3.3068x; 1.2078x over previous
//
#include <hip/hip_runtime.h>
#include <math.h>

namespace {

constexpr int B_ = 64;
constexpr int C_ = 192;
constexpr int H_ = 56;
constexpr int W_ = 56;
constexpr int HW_ = H_ * W_;          // 3136
constexpr int CHW_ = C_ * HW_;        // 602112
constexpr float PI_F = 3.14159265358979323846f;

typedef __attribute__((ext_vector_type(8))) short short8;
typedef __attribute__((ext_vector_type(4))) short short4v;
typedef __attribute__((ext_vector_type(4))) float f32x4;

__device__ inline unsigned short f2bf(float f) {
  union { float f; unsigned u; } v{f};
  unsigned r = v.u + 0x7FFFu + ((v.u >> 16) & 1u);
  return (unsigned short)(r >> 16);
}

// XOR swizzle for [row][c] bf16 tiles, row stride 200 elems (16B granular)
__device__ inline int swz(int row) { return ((row >> 1) & 7) << 3; }

// ---------------------------------------------------------------------------
// K0: DCT-II basis table
// ---------------------------------------------------------------------------
__global__ void k_tables(float* __restrict__ cos_tab) {
  int i = blockIdx.x * 256 + threadIdx.x;
  if (i >= HW_) return;
  int n = i / W_;
  int x = i - n * W_;
  float wx = ((float)x + 0.5f) / 56.0f;
  float v = cosf(((float)n * wx) * PI_F) * 0.18898223650461362f;
  if (n == 0) v *= 0.7071067811865476f;
  cos_tab[i] = v;
}

// ---------------------------------------------------------------------------
// K_wexp: wexp[c][hw] = exp(-relu(fe@tok_w+tok_b) * (n^2+m^2))
// ---------------------------------------------------------------------------
__global__ __launch_bounds__(192) void k_wexp(const float* __restrict__ fe,
                                              const float* __restrict__ tkw,
                                              const float* __restrict__ tkb,
                                              float* __restrict__ wexp) {
  __shared__ float sfe[16][C_];
  int hw0 = blockIdx.x * 16;
  int t = threadIdx.x;
  for (int p = 0; p < 16; ++p) sfe[p][t] = fe[(size_t)(hw0 + p) * C_ + t];
  __syncthreads();
  float acc[16];
#pragma unroll
  for (int p = 0; p < 16; ++p) acc[p] = 0.f;
  for (int i = 0; i < C_; ++i) {
    float wv = tkw[i * C_ + t];
#pragma unroll
    for (int p = 0; p < 16; ++p) acc[p] = fmaf(sfe[p][i], wv, acc[p]);
  }
  float bias = tkb[t];
  const float step = PI_F / 56.0f;
#pragma unroll
  for (int p = 0; p < 16; ++p) {
    int hw = hw0 + p;
    int hh = hw / W_;
    int ww = hw - hh * W_;
    float nh = step * (float)hh;
    float nm = step * (float)ww;
    float a = nh * nh + nm * nm;
    float k = fmaxf(acc[p] + bias, 0.0f);
    wexp[(size_t)t * HW_ + hw] = expf(-k * a);
  }
}

// ---------------------------------------------------------------------------
// K_prep_w: lwT[j][c] = bf16(lin_w[c][j]), owT[j][c] = bf16(out_w[c][j])
// ---------------------------------------------------------------------------
__global__ __launch_bounds__(256) void k_prep_w(const float* __restrict__ lw,
                                                const float* __restrict__ ow,
                                                unsigned short* __restrict__ lwT,
                                                unsigned short* __restrict__ owT) {
  int i = blockIdx.x * 256 + threadIdx.x;
  if (i < 384 * 192) {
    int j = i / 192, c = i - j * 192;
    lwT[i] = f2bf(lw[c * 384 + j]);
  } else if (i < 384 * 192 + 192 * 192) {
    int k = i - 384 * 192;
    int j = k / 192, c = k - j * 192;
    owT[k] = f2bf(ow[c * 192 + j]);
  }
}

// ---------------------------------------------------------------------------
// K1: fused depthwise 3x3 conv + bias + transpose-to-bf16 (v2).
// ---------------------------------------------------------------------------
__global__ __launch_bounds__(512) void k_convt(const float* __restrict__ x,
                                               const float* __restrict__ dww,
                                               const float* __restrict__ dwb,
                                               unsigned short* __restrict__ yT) {
  __shared__ unsigned short t[64 * 200];
  int b = blockIdx.y, pt = blockIdx.x;
  int tid = threadIdx.x;
  int p = tid & 63, cr = tid >> 6;
  int pos = pt * 64 + p;
  int h = pos / 56, w = pos - h * 56;
  bool hn = h > 0, hp = h < 55, wn = w > 0, wq = w < 55;
  int o00 = (hn && wn) ? -57 : 0, o01 = hn ? -56 : 0, o02 = (hn && wq) ? -55 : 0;
  int o10 = wn ? -1 : 0, o12 = wq ? 1 : 0;
  int o20 = (hp && wn) ? 55 : 0, o21 = hp ? 56 : 0, o22 = (hp && wq) ? 57 : 0;
  float f00 = (hn && wn) ? 1.f : 0.f, f01 = hn ? 1.f : 0.f, f02 = (hn && wq) ? 1.f : 0.f;
  float f10 = wn ? 1.f : 0.f, f12 = wq ? 1.f : 0.f;
  float f20 = (hp && wn) ? 1.f : 0.f, f21 = hp ? 1.f : 0.f, f22 = (hp && wq) ? 1.f : 0.f;
  const float* xb = x + (size_t)b * CHW_ + pos;
#pragma unroll
  for (int q = 0; q < 3; ++q) {
    short8 vv;
#pragma unroll
    for (int e = 0; e < 8; ++e) {
      int c = cr * 24 + q * 8 + e;
      const float* xc = xb + (size_t)c * HW_;
      const float* w9 = dww + c * 9;
      float v0 = xc[o00], v1 = xc[o01], v2 = xc[o02];
      float v3 = xc[o10], v4 = xc[0], v5 = xc[o12];
      float v6 = xc[o20], v7 = xc[o21], v8 = xc[o22];
      float a = dwb[c];
      a = fmaf(v0 * f00, w9[0], a);
      a = fmaf(v1 * f01, w9[1], a);
      a = fmaf(v2 * f02, w9[2], a);
      a = fmaf(v3 * f10, w9[3], a);
      a = fmaf(v4, w9[4], a);
      a = fmaf(v5 * f12, w9[5], a);
      a = fmaf(v6 * f20, w9[6], a);
      a = fmaf(v7 * f21, w9[7], a);
      a = fmaf(v8 * f22, w9[8], a);
      vv[e] = (short)f2bf(a);
    }
    *(short8*)&t[p * 200 + ((cr * 24 + q * 8) ^ swz(p))] = vv;
  }
  __syncthreads();
  unsigned short* o = yT + ((size_t)b * HW_ + pt * 64) * C_;
#pragma unroll
  for (int q = 0; q < 3; ++q) {
    int idx = q * 512 + tid;
    int pp = idx / 24, cb = idx - pp * 24;
    short8 v = *(const short8*)&t[pp * 200 + ((cb * 8) ^ swz(pp))];
    *(short8*)&o[(size_t)idx * 8] = v;
  }
}

// ---------------------------------------------------------------------------
// K2: GEMM1 via MFMA bf16.
// ---------------------------------------------------------------------------
__global__ __launch_bounds__(256) void k_gemm1(const unsigned short* __restrict__ yT,
                                               const unsigned short* __restrict__ lwT,
                                               const float* __restrict__ lb,
                                               float* __restrict__ xp,
                                               float* __restrict__ zb) {
  constexpr int LD = 40;
  __shared__ unsigned short sA[128 * LD];
  __shared__ unsigned short sY[128 * LD];
  int b = blockIdx.y;
  int bx = blockIdx.x;
  int xcd = bx & 7, o8 = bx >> 3;
  int lg = (xcd < 3 ? xcd * 10 : 30 + (xcd - 3) * 9) + o8;
  int pt = lg / 3, jt = lg % 3;
  int pos0 = pt * 128, j0 = jt * 128;
  int tid = threadIdx.x, lane = tid & 63, wv = tid >> 6;
  int wm = wv & 1, wn = wv >> 1;

  int row0 = tid >> 2, row1 = 64 + (tid >> 2), cb = (tid & 3) * 8;
  const unsigned short* a0 = lwT + (size_t)(j0 + row0) * C_ + cb;
  const unsigned short* a1 = lwT + (size_t)(j0 + row1) * C_ + cb;
  int pr0 = pos0 + row0; if (pr0 > HW_ - 1) pr0 = HW_ - 1;
  int pr1 = pos0 + row1; if (pr1 > HW_ - 1) pr1 = HW_ - 1;
  const unsigned short* b0 = yT + ((size_t)b * HW_ + pr0) * C_ + cb;
  const unsigned short* b1 = yT + ((size_t)b * HW_ + pr1) * C_ + cb;
  int d0 = row0 * LD + cb, d1 = row1 * LD + cb;

  f32x4 acc[4][4] = {};
  for (int kk = 0; kk < C_; kk += 32) {
    short8 va0 = *(const short8*)(a0 + kk);
    short8 va1 = *(const short8*)(a1 + kk);
    short8 vb0 = *(const short8*)(b0 + kk);
    short8 vb1 = *(const short8*)(b1 + kk);
    if (kk) __syncthreads();
    *(short8*)&sA[d0] = va0;
    *(short8*)&sA[d1] = va1;
    *(short8*)&sY[d0] = vb0;
    *(short8*)&sY[d1] = vb1;
    __syncthreads();
    int ra = (wm * 64 + (lane & 15)) * LD + (lane >> 4) * 8;
    int rb = (wn * 64 + (lane & 15)) * LD + (lane >> 4) * 8;
    short8 af[4], bf[4];
#pragma unroll
    for (int m = 0; m < 4; ++m) af[m] = *(const short8*)&sA[ra + m * 16 * LD];
#pragma unroll
    for (int n = 0; n < 4; ++n) bf[n] = *(const short8*)&sY[rb + n * 16 * LD];
#pragma unroll
    for (int m = 0; m < 4; ++m)
#pragma unroll
      for (int n = 0; n < 4; ++n)
        acc[m][n] = __builtin_amdgcn_mfma_f32_16x16x32_bf16(af[m], bf[n], acc[m][n], 0, 0, 0);
  }

#pragma unroll
  for (int m = 0; m < 4; ++m) {
    int jb = j0 + wm * 64 + m * 16 + (lane >> 4) * 4;
#pragma unroll
    for (int r = 0; r < 4; ++r) {
      int jg = jb + r;
      float bias = lb[jg];
      float* base = (jg < C_) ? (xp + ((size_t)b * C_ + jg) * HW_)
                              : (zb + ((size_t)b * C_ + (jg - C_)) * HW_);
#pragma unroll
      for (int n = 0; n < 4; ++n) {
        int pos = pos0 + wn * 64 + n * 16 + (lane & 15);
        if (pos < HW_) base[pos] = acc[m][n][r] + bias;
      }
    }
  }
}

// ---------------------------------------------------------------------------
// K4 (v2): spectral sandwich via bf16 MFMA, per (b,c) plane, in-place d_out.
// S = Cn^T ((Cn P Cm^T) .* W) Cm, all matmuls 56^3 padded to 64^3.
// D = mfma(A rows r (k contig), B rows s (k contig)) -> D[r][s],
// C-layout col=lane&15, row=(lane>>4)*4+reg.
// Stage2 output stored TRANSPOSED (packed short4) so stage3 B is k-contig.
// ---------------------------------------------------------------------------
__global__ __launch_bounds__(256) void k_spec(const float* xp,
                                              const float* __restrict__ cos_tab,
                                              const float* __restrict__ wexp,
                                              float* sout) {
  constexpr int LDT = 72;
  __shared__ unsigned short lds[4 * 64 * LDT];
  __shared__ float sW[56 * 57];
  unsigned short* sCn = lds;                 // [n][h] = cos[n][h]
  unsigned short* sCt = lds + 64 * LDT;      // [h][n] = cos[n][h]
  unsigned short* sP  = lds + 2 * 64 * LDT;  // [w][h] = P[h][w]
  unsigned short* sT  = lds + 3 * 64 * LDT;  // intermediate
  const int tid = threadIdx.x;
  const int bc = blockIdx.x;
  const int c = bc % C_;

  {  // zero pad regions (whole bf16 area)
    uint2* z = (uint2*)lds;
    for (int i = tid; i < 4608; i += 256) z[i] = make_uint2(0u, 0u);
  }
  __syncthreads();

  const float* Pp = xp + (size_t)bc * HW_;
  const float* Wp = wexp + (size_t)c * HW_;
  for (int e = tid; e < HW_; e += 256) {
    int n = e / 56, m = e - n * 56;
    unsigned short cv = f2bf(cos_tab[e]);
    sCn[n * LDT + m] = cv;
    sCt[m * LDT + n] = cv;
    sP[m * LDT + n] = f2bf(Pp[e]);
    sW[n * 57 + m] = Wp[e];
  }
  __syncthreads();

  const int lane = tid & 63, wv = tid >> 6;
  const int wm = wv & 1, wn = wv >> 1;
  const int lr = lane & 15, lk = lane >> 4;
  const int rt0 = wm * 2, ct0 = wn * 2;
  short8 af[2][2], bg[2][2];
  f32x4 acc[2][2];

#define LOADFRAGS(Ab, Bb)                                                        \
  {                                                                              \
    _Pragma("unroll") for (int i = 0; i < 2; ++i) {                              \
      _Pragma("unroll") for (int k = 0; k < 2; ++k) {                            \
        af[i][k] = *(const short8*)&Ab[((rt0 + i) * 16 + lr) * LDT + k * 32 + lk * 8]; \
        bg[i][k] = *(const short8*)&Bb[((ct0 + i) * 16 + lr) * LDT + k * 32 + lk * 8]; \
      }                                                                          \
    }                                                                            \
  }
#define DOMFMA()                                                                 \
  {                                                                              \
    _Pragma("unroll") for (int i = 0; i < 2; ++i) {                              \
      _Pragma("unroll") for (int j = 0; j < 2; ++j) {                            \
        acc[i][j] = {};                                                          \
        acc[i][j] = __builtin_amdgcn_mfma_f32_16x16x32_bf16(af[i][0], bg[j][0], acc[i][j], 0, 0, 0); \
        acc[i][j] = __builtin_amdgcn_mfma_f32_16x16x32_bf16(af[i][1], bg[j][1], acc[i][j], 0, 0, 0); \
      }                                                                          \
    }                                                                            \
  }

  // stage 1: D1[n][w] = sum_h Cn[n][h] * P^T[w][h]  -> sT[n][w]
  LOADFRAGS(sCn, sP);
  __syncthreads();
  DOMFMA();
#pragma unroll
  for (int i = 0; i < 2; ++i)
#pragma unroll
    for (int j = 0; j < 2; ++j)
#pragma unroll
      for (int r = 0; r < 4; ++r)
        sT[((rt0 + i) * 16 + lk * 4 + r) * LDT + (ct0 + j) * 16 + lr] = f2bf(acc[i][j][r]);
  __syncthreads();

  // stage 2: D2[n][m] = sum_w T1[n][w] * Cm[m][w]; gate by W; store sT[m][n]
  LOADFRAGS(sT, sCn);
  __syncthreads();
  DOMFMA();
#pragma unroll
  for (int i = 0; i < 2; ++i)
#pragma unroll
    for (int j = 0; j < 2; ++j) {
      int n0 = (rt0 + i) * 16 + lk * 4;
      int m = (ct0 + j) * 16 + lr;
      int mc = m < 56 ? m : 55;
      short4v pk;
#pragma unroll
      for (int r = 0; r < 4; ++r) {
        int n = n0 + r;
        int nc = n < 56 ? n : 55;
        pk[r] = (short)f2bf(acc[i][j][r] * sW[nc * 57 + mc]);
      }
      *(short4v*)&sT[m * LDT + n0] = pk;
    }
  __syncthreads();

  // stage 3: D3[h][m] = sum_n CnT[h][n] * T2T[m][n]  -> sT[h][m]
  LOADFRAGS(sCt, sT);
  __syncthreads();
  DOMFMA();
#pragma unroll
  for (int i = 0; i < 2; ++i)
#pragma unroll
    for (int j = 0; j < 2; ++j)
#pragma unroll
      for (int r = 0; r < 4; ++r)
        sT[((rt0 + i) * 16 + lk * 4 + r) * LDT + (ct0 + j) * 16 + lr] = f2bf(acc[i][j][r]);
  __syncthreads();

  // stage 4: D4[h][w] = sum_m T3[h][m] * CmT[w][m]  -> global S[h][w]
  LOADFRAGS(sT, sCt);
  DOMFMA();
  float* So = sout + (size_t)bc * HW_;
#pragma unroll
  for (int i = 0; i < 2; ++i)
#pragma unroll
    for (int j = 0; j < 2; ++j) {
      int w = (ct0 + j) * 16 + lr;
      if (w < 56) {
#pragma unroll
        for (int r = 0; r < 4; ++r) {
          int h = (rt0 + i) * 16 + lk * 4 + r;
          if (h < 56) So[h * 56 + w] = acc[i][j][r];
        }
      }
    }
#undef LOADFRAGS
#undef DOMFMA
}

// ---------------------------------------------------------------------------
// K5: LayerNorm -> silu-gate -> GEMM2 via MFMA bf16.
// ---------------------------------------------------------------------------
__global__ __launch_bounds__(256) void k_ln2(const float* s,
                                             const float* __restrict__ z,
                                             const float* __restrict__ gamma,
                                             const float* __restrict__ beta,
                                             const unsigned short* __restrict__ owT,
                                             const float* __restrict__ ob,
                                             float* out) {
  __shared__ unsigned short act[64 * 200];
  __shared__ float red[8][64];
  __shared__ float smu[64], srs[64];
  int b = blockIdx.y, pt = blockIdx.x;
  int tid = threadIdx.x, lane = tid & 63, wv = tid >> 6;
  int p = lane, cr = wv;
  const float* sp = s + (size_t)b * CHW_ + (size_t)(48 * cr) * HW_ + pt * 64 + p;
  const float* zp = z + (size_t)b * CHW_ + (size_t)(48 * cr) * HW_ + pt * 64 + p;
  float sv[48];
  float sum = 0.f, sq = 0.f;
#pragma unroll
  for (int i = 0; i < 48; ++i) {
    float v = sp[(size_t)i * HW_];
    sv[i] = v;
    sum += v;
    sq = fmaf(v, v, sq);
  }
  red[cr][p] = sum;
  red[4 + cr][p] = sq;
  __syncthreads();
  if (tid < 64) {
    float s1 = red[0][tid] + red[1][tid] + red[2][tid] + red[3][tid];
    float s2 = red[4][tid] + red[5][tid] + red[6][tid] + red[7][tid];
    float mu = s1 * (1.0f / 192.0f);
    float var = s2 * (1.0f / 192.0f) - mu * mu;
    smu[tid] = mu;
    srs[tid] = rsqrtf(var + 1e-5f);
  }
  __syncthreads();
  float mu = smu[p], rs = srs[p];
#pragma unroll
  for (int q = 0; q < 6; ++q) {
    short8 vv;
#pragma unroll
    for (int e = 0; e < 8; ++e) {
      int i = 8 * q + e;
      int c = 48 * cr + i;
      float v = (sv[i] - mu) * rs * gamma[c] + beta[c];
      float zz = zp[(size_t)i * HW_];
      v *= zz / (1.0f + expf(-zz));
      vv[e] = (short)f2bf(v);
    }
    *(short8*)&act[p * 200 + ((48 * cr + 8 * q) ^ swz(p))] = vv;
  }
  __syncthreads();

  f32x4 acc[3][4] = {};
  const unsigned short* ap = owT + (size_t)(wv * 48 + (lane & 15)) * C_ + (lane >> 4) * 8;
#pragma unroll
  for (int kk = 0; kk < C_; kk += 32) {
    short8 af[3], bf[4];
#pragma unroll
    for (int m = 0; m < 3; ++m) af[m] = *(const short8*)(ap + m * 16 * C_ + kk);
#pragma unroll
    for (int n = 0; n < 4; ++n) {
      int row = (lane & 15) + 16 * n;
      int co = (kk + (lane >> 4) * 8) ^ swz(row);
      bf[n] = *(const short8*)&act[row * 200 + co];
    }
#pragma unroll
    for (int m = 0; m < 3; ++m)
#pragma unroll
      for (int n = 0; n < 4; ++n)
        acc[m][n] = __builtin_amdgcn_mfma_f32_16x16x32_bf16(af[m], bf[n], acc[m][n], 0, 0, 0);
  }

  float* op = out + (size_t)b * CHW_ + pt * 64;
#pragma unroll
  for (int m = 0; m < 3; ++m) {
    int jb = wv * 48 + m * 16 + (lane >> 4) * 4;
#pragma unroll
    for (int r = 0; r < 4; ++r) {
      int j = jb + r;
      float bias = ob[j];
#pragma unroll
      for (int n = 0; n < 4; ++n) {
        int pos = n * 16 + (lane & 15);
        op[(size_t)j * HW_ + pos] = acc[m][n][r] + bias;
      }
    }
  }
}

}  // namespace

extern "C" void kernel_launch(void* const* d_in, const int* in_sizes, int n_in,
                              void* d_out, int out_size, void* d_ws, size_t ws_size,
                              hipStream_t stream) {
  const float* x = (const float*)d_in[0];
  const float* dww = (const float*)d_in[1];
  const float* dwb = (const float*)d_in[2];
  const float* lw = (const float*)d_in[3];
  const float* lb = (const float*)d_in[4];
  const float* tkw = (const float*)d_in[5];
  const float* tkb = (const float*)d_in[6];
  const float* fe = (const float*)d_in[7];
  const float* gamma = (const float*)d_in[8];
  const float* beta = (const float*)d_in[9];
  const float* ow = (const float*)d_in[10];
  const float* obias = (const float*)d_in[11];
  float* out = (float*)d_out;

  float* ws = (float*)d_ws;
  float* cos_tab = ws;                                  // 3136 f
  float* wexp = cos_tab + HW_;                          // 602112 f
  float* zb = wexp + CHW_;                              // 38535168 f
  unsigned short* lwT = (unsigned short*)(zb + (size_t)B_ * CHW_);  // 73728 u16
  unsigned short* owT = lwT + 384 * C_;                 // 36864 u16
  unsigned short* yT = owT + C_ * C_;                   // 38535168 u16

  hipLaunchKernelGGL(k_tables, dim3(13), dim3(256), 0, stream, cos_tab);
  hipLaunchKernelGGL(k_wexp, dim3(HW_ / 16), dim3(192), 0, stream, fe, tkw, tkb, wexp);
  hipLaunchKernelGGL(k_prep_w, dim3(432), dim3(256), 0, stream, lw, ow, lwT, owT);
  hipLaunchKernelGGL(k_convt, dim3(HW_ / 64, B_), dim3(512), 0, stream, x, dww, dwb, yT);
  hipLaunchKernelGGL(k_gemm1, dim3(75, B_), dim3(256), 0, stream, yT, lwT, lb, out, zb);
  hipLaunchKernelGGL(k_spec, dim3(B_ * C_), dim3(256), 0, stream, out, cos_tab, wexp, out);
  hipLaunchKernelGGL(k_ln2, dim3(HW_ / 64, B_), dim3(256), 0, stream, out, zb, gamma, beta,
                     owT, obias, out);
}